// Round 8
// baseline (1153.078 us; speedup 1.0000x reference)
//
#include <hip/hip_runtime.h>
#include <cstdint>
#include <cmath>

#define HW 64
#define NPIX 4096          // 64*64
#define CIN 512
#define NANCH 36864        // 4096*9
#define PREN 3000
#define POSTN 300
#define ICL 8
#define NSLOT 13           // ceil(8*6*66 / 256), last slot: 96 threads

typedef _Float16 h8v __attribute__((ext_vector_type(8)));
typedef float f16v __attribute__((ext_vector_type(16)));

#define AS1 __attribute__((address_space(1)))
#define AS3 __attribute__((address_space(3)))

__device__ __forceinline__ void gl16(const void* g, void* l) {
  __builtin_amdgcn_global_load_lds((const AS1 void*)g, (AS3 void*)l, 16, 0, 0);
}

// f16 two-term split: f = h + l with |f-h-l| <= |f|*2^-22 (f pre-scaled so
// both h and l stay in f16 normal range; scaling by 2^k is exact).
__device__ __forceinline__ void f16_split(float f, short& h, short& l) {
  _Float16 hh = (_Float16)f;
  float hf = (float)hh;
  _Float16 ll = (_Float16)(f - hf);
  h = __builtin_bit_cast(short, hh);
  l = __builtin_bit_cast(short, ll);
}

// ==================== MFMA PATH: f16x2-split conv ====================

// ---- w (512oc,512ic,3,3) fp32 -> wth/wtl fragment-major f16 hi/lo, x128 ----
// Layout (shorts): [tap][icc][kh][lh][oc 0..511][8 ic]
__global__ __launch_bounds__(256) void xform_w_kernel(
    const float* __restrict__ w, short* __restrict__ wth,
    short* __restrict__ wtl, unsigned* __restrict__ zp) {
  const int oc = blockIdx.x;
  const int t = threadIdx.x;
  __shared__ float ws_[4608];
  const float* wr = w + (size_t)oc * 4608;
  for (int i = t; i < 4608; i += 256) ws_[i] = wr[i];
  __syncthreads();
  for (int c = t; c < 576; c += 256) {
    int tap = c / 64;
    int g = c - tap * 64;            // ic-group of 8: ic = g*8 .. g*8+7
    int icc = g >> 2;
    int kh = (g >> 1) & 1;
    int lhh = g & 1;
    h8v hv, lv;
    short* hp = (short*)&hv;
    short* lp = (short*)&lv;
#pragma unroll
    for (int j = 0; j < 8; ++j) {
      short hh, ll;
      f16_split(ws_[(g * 8 + j) * 9 + tap] * 128.0f, hh, ll);
      hp[j] = hh; lp[j] = ll;
    }
    long o = (((((long)tap * 16 + icc) * 2 + kh) * 2 + lhh) * 512 + oc) * 8;
    *(h8v*)(wth + o) = hv;
    *(h8v*)(wtl + o) = lv;
  }
  if (oc == 0 && t < 16) zp[t] = 0u;   // zero-page for halo redirect
}

// ---- x NCHW fp32 -> xth/xtl [n][y][x][ic] f16 hi/lo (NHWC), x2048 ----
__global__ __launch_bounds__(256) void xform_x_kernel(
    const float* __restrict__ x, short* __restrict__ xth,
    short* __restrict__ xtl) {
  const int yb = blockIdx.x;   // 0..63
  const int n = blockIdx.y;
  const int t = threadIdx.x;
  __shared__ float xs[64 * 65];
  const float* xr = x + ((size_t)n * 512) * 4096 + yb * 64;
  short* oh = xth + ((size_t)n * 4096 + yb * 64) * 512;
  short* ol = xtl + ((size_t)n * 4096 + yb * 64) * 512;
  for (int icb = 0; icb < 8; ++icb) {
    if (icb) __syncthreads();
#pragma unroll
    for (int q = 0; q < 16; ++q) {
      int idx = q * 256 + t;
      int icl = idx >> 6, xc = idx & 63;
      xs[icl * 65 + xc] = xr[(size_t)(icb * 64 + icl) * 4096 + xc];
    }
    __syncthreads();
#pragma unroll
    for (int q = 0; q < 2; ++q) {
      int c = q * 256 + t;
      int xc = c >> 3, icg = c & 7;
      h8v hv, lv;
      short* hp = (short*)&hv;
      short* lp = (short*)&lv;
#pragma unroll
      for (int j = 0; j < 8; ++j) {
        short hh, ll;
        f16_split(xs[(icg * 8 + j) * 65 + xc] * 2048.0f, hh, ll);
        hp[j] = hh; lp[j] = ll;
      }
      size_t o = (size_t)xc * 512 + icb * 64 + icg * 8;
      *(h8v*)(oh + o) = hv;
      *(h8v*)(ol + o) = lv;
    }
  }
}

// ---- 3x3 conv via implicit GEMM on matrix cores, f16x2 split (3 MFMA) ----
// grid (32 ypair-raw, 4, 4n), 256 thr = 4 waves; block tile 2rows x 64cols x 128oc.
// A-slab: LDS, DOUBLE-buffered [abuf][hilo][4row x 68col][32ic] (69632 B).
// B: global->VGPR in fragment layout (L2-resident), prefetched 1 tap ahead.
// R8 schedule: per tap {B-prefetch(t+1); (tap==0: gl16 next-icc A -> buf^1);
// A-frag reg-prefetch(t+1); setprio(1); 24 MFMA on regs; setprio(0)}.
// ONE barrier per icc (gl16s issued 9 taps earlier -> drain free).
// Steady-state wave critical path = MFMA issue only.
// Result scaled 2^18; chunked S-drain per icc (bit-identical to R3 order).
__global__ __launch_bounds__(256, 2) void conv3_mfma(
    const short* __restrict__ xth, const short* __restrict__ xtl,
    const short* __restrict__ wth, const short* __restrict__ wtl,
    const float* __restrict__ bconv, const char* __restrict__ zpage,
    float* __restrict__ feat2) {
  const int t = threadIdx.x;
  const int lane = t & 63;
  const int wid = __builtin_amdgcn_readfirstlane(t >> 6);
  const int l31 = lane & 31, lh = lane >> 5;
  const int wm = wid >> 1, wn = wid & 1;

  // XCD-aware swizzle: each XCD (bx%8) owns one 128-oc weight panel (L2-fit).
  const int bx = blockIdx.x, by = blockIdx.y, n = blockIdx.z;
  const int k8 = bx & 7;
  const int ocb = k8 & 3;
  const int yp = (k8 >> 2) * 16 + (bx >> 3) * 4 + by;  // 0..31
  const int y0 = yp * 2;
  const int ocbase = ocb * 128;

  __shared__ short As[2][2][272 * 32];   // [abuf][hilo][...] 69632 B
  char* const asb = (char*)&As[0][0][0];

  // ---- A staging descriptors: 34x 1KB blocks over 4 waves ----
  const char* asrc[9]; int adst[9]; int astep[9];
  {
    const char* xs0 = (const char*)xth;
    const char* xs1 = (const char*)xtl;
#pragma unroll
    for (int k = 0; k < 9; ++k) {
      int bq = wid + 4 * k;
      if (bq < 34) {
        int hl = (bq >= 17) ? 1 : 0;
        int blk = bq - hl * 17;
        int e = blk * 16 + (lane >> 2);
        int slot = lane & 3;
        int r = e / 68;
        int cp = e - r * 68;
        int y = y0 - 1 + r;
        int c = cp - 1;
        bool valid = (cp >= 1) && (cp <= 64) && (y >= 0) && (y < 64);
        int ss = slot ^ ((e >> 1) & 3);                 // source pre-swizzle
        long off = ((((long)n * 64 + y) * 64 + c) * 512 + ss * 8) * 2;
        asrc[k] = valid ? ((hl ? xs1 : xs0) + off) : (const char*)zpage;
        astep[k] = valid ? 64 : 0;                      // 32 ic * 2B per icc
        adst[k] = hl * 17408 + blk * 1024;
      }
    }
  }

  // ---- B fragment global base: lane-constant offset (shorts) ----
  const long lane_b = (long)lh * 4096 + (long)(ocbase + wn * 64 + l31) * 8;

  struct FragB { h8v h[2][2], l[2][2]; };   // [kh][fn]
  struct FragA { h8v h[2][2], l[2][2]; };   // [kh][fm]

#define READ_Bg(F, TAP, ICC) do {                                            \
    long sb_ = ((long)(TAP) * 16 + (ICC)) * 16384 + lane_b;                  \
    _Pragma("unroll")                                                        \
    for (int kh_ = 0; kh_ < 2; ++kh_)                                        \
      _Pragma("unroll")                                                      \
      for (int fn_ = 0; fn_ < 2; ++fn_) {                                    \
        long o_ = sb_ + kh_ * 8192 + fn_ * 256;                              \
        (F).h[kh_][fn_] = *(const h8v*)(wth + o_);                           \
        (F).l[kh_][fn_] = *(const h8v*)(wtl + o_);                           \
      }                                                                      \
  } while (0)

#define COMP_AE(AE, TAP) do {                                                 \
    int dy_ = (TAP) / 3, dx_ = (TAP) - dy_ * 3;                               \
    _Pragma("unroll")                                                         \
    for (int fm_ = 0; fm_ < 2; ++fm_) {                                       \
      int e_ = (wm + dy_) * 68 + fm_ * 32 + l31 + dx_;                        \
      (AE)[fm_] = e_ * 64 + ((lh ^ ((e_ >> 1) & 3)) << 4);                    \
    }                                                                         \
  } while (0)

#define READ_Af(F, AE, AB) do {                                               \
    _Pragma("unroll")                                                         \
    for (int kh_ = 0; kh_ < 2; ++kh_)                                         \
      _Pragma("unroll")                                                       \
      for (int fm_ = 0; fm_ < 2; ++fm_) {                                     \
        int a0_ = (AE)[fm_] ^ (kh_ << 5);                                     \
        (F).h[kh_][fm_] = *(const h8v*)((AB) + a0_);                          \
        (F).l[kh_][fm_] = *(const h8v*)((AB) + 17408 + a0_);                  \
      }                                                                       \
  } while (0)

  // 24 MFMAs on registers only; per-acc order identical to R3 (bit-exact).
#define TAP_MFMA(FA, BC) do {                                                 \
    _Pragma("unroll")                                                         \
    for (int kh_ = 0; kh_ < 2; ++kh_) {                                       \
      _Pragma("unroll")                                                       \
      for (int fm_ = 0; fm_ < 2; ++fm_)                                       \
        _Pragma("unroll")                                                     \
        for (int fn_ = 0; fn_ < 2; ++fn_)                                     \
          acc[fm_][fn_] = __builtin_amdgcn_mfma_f32_32x32x16_f16(             \
              (FA).h[kh_][fm_], (BC).h[kh_][fn_], acc[fm_][fn_], 0, 0, 0);    \
      _Pragma("unroll")                                                       \
      for (int fm_ = 0; fm_ < 2; ++fm_)                                       \
        _Pragma("unroll")                                                     \
        for (int fn_ = 0; fn_ < 2; ++fn_)                                     \
          acc[fm_][fn_] = __builtin_amdgcn_mfma_f32_32x32x16_f16(             \
              (FA).l[kh_][fm_], (BC).h[kh_][fn_], acc[fm_][fn_], 0, 0, 0);    \
      _Pragma("unroll")                                                       \
      for (int fm_ = 0; fm_ < 2; ++fm_)                                       \
        _Pragma("unroll")                                                     \
        for (int fn_ = 0; fn_ < 2; ++fn_)                                     \
          acc[fm_][fn_] = __builtin_amdgcn_mfma_f32_32x32x16_f16(             \
              (FA).h[kh_][fm_], (BC).l[kh_][fn_], acc[fm_][fn_], 0, 0, 0);    \
    }                                                                         \
  } while (0)

  f16v acc[2][2];   // per-icc chunk accumulator (MFMA C)
  f16v S[2][2];     // running sum across chunks
#pragma unroll
  for (int i = 0; i < 2; ++i)
#pragma unroll
    for (int j = 0; j < 2; ++j)
#pragma unroll
      for (int r = 0; r < 16; ++r) { acc[i][j][r] = 0.f; S[i][j][r] = 0.f; }

  // prologue: A(icc=0) -> buf0; B(0,0) -> regs; first tap-0 A-frags
#pragma unroll
  for (int k = 0; k < 9; ++k) {
    int bq = wid + 4 * k;
    if (bq < 34) gl16(asrc[k], asb + adst[k]);
  }
  FragB Bcur, Bnxt;
  FragA Fcur, Fnxt;
  READ_Bg(Bcur, 0, 0);
  __syncthreads();
  int ae[2], aeN[2];
  COMP_AE(ae, 0);
  READ_Af(Fcur, ae, asb);
  int acur = 0;

#pragma unroll 1
  for (int icc = 0; icc < 16; ++icc) {
    char* const abase = asb + acur * 34816;
    char* const abnxt = asb + (acur ^ 1) * 34816;
#pragma unroll
    for (int tap = 0; tap < 9; ++tap) {
      const int tapN = (tap < 8) ? tap + 1 : 0;
      const int iccN = (tap < 8) ? icc : ((icc < 15) ? icc + 1 : 15);
      READ_Bg(Bnxt, tapN, iccN);            // per-wave B prefetch (1 ahead)
      if (tap == 0 && icc < 15) {           // stage NEXT icc A -> other buf
#pragma unroll
        for (int k = 0; k < 9; ++k) {
          int bq = wid + 4 * k;
          if (bq < 34) { asrc[k] += astep[k]; gl16(asrc[k], abnxt + adst[k]); }
        }
      }
      if (tap < 8) {                        // A-frag reg prefetch (1 ahead)
        COMP_AE(aeN, tap + 1);
        READ_Af(Fnxt, aeN, abase);
      }
      __builtin_amdgcn_s_setprio(1);
      TAP_MFMA(Fcur, Bcur);
      __builtin_amdgcn_s_setprio(0);
      Fcur = Fnxt;                          // SSA-renamed under full unroll
      Bcur = Bnxt;
    }
    // drain chunk accumulator into S (same position as R3 -> bit-exact)
#pragma unroll
    for (int fm = 0; fm < 2; ++fm)
#pragma unroll
      for (int fn = 0; fn < 2; ++fn)
#pragma unroll
        for (int r = 0; r < 16; ++r) {
          S[fm][fn][r] += acc[fm][fn][r];
          acc[fm][fn][r] = 0.f;
        }
    __syncthreads();      // gl16s (issued 9 taps ago) drain ~free; flip safe
    acur ^= 1;
    if (icc < 15) {       // first-tap frags of the new slab
      COMP_AE(ae, 0);
      READ_Af(Fcur, ae, asb + acur * 34816);
    }
  }

#undef READ_Bg
#undef COMP_AE
#undef READ_Af
#undef TAP_MFMA

  // ---- epilogue: unscale + bias + ReLU -> feat2 NHWC ----
  const float OS = 1.0f / 262144.0f;       // 2^-18 (x*2^11 * w*2^7)
  const float* bb = bconv + ocbase + wn * 64;
#pragma unroll
  for (int fn = 0; fn < 2; ++fn) {
    const float bias = bb[fn * 32 + l31];
#pragma unroll
    for (int fm = 0; fm < 2; ++fm) {
      float* op = feat2 + (((long)n * 4096 + (y0 + wm) * 64 + fm * 32) * 512)
                + ocbase + wn * 64 + fn * 32 + l31;
#pragma unroll
      for (int r = 0; r < 16; ++r) {
        int m = (r & 3) + 8 * (r >> 2) + 4 * lh;
        op[(long)m * 512] = fmaxf(S[fm][fn][r] * OS + bias, 0.f);
      }
    }
  }
}

__global__ __launch_bounds__(256) void zero_hist_kernel(unsigned* __restrict__ h) {
  int i = blockIdx.x * 256 + threadIdx.x;
  if (i < 262160) h[i] = 0u;
}

// ============== OLD PATH (fallback if ws_size is too small) ==============
__global__ __launch_bounds__(256) void reshape_w_kernel(
    const float* __restrict__ w, float* __restrict__ w4,
    unsigned* __restrict__ histz) {
  int gid = blockIdx.x * 256 + threadIdx.x;
  if (gid < 262160) histz[gid] = 0;
  if (gid >= 512 * 512 * 9) return;
  int o4  = gid & 3;
  int r   = gid >> 2;
  int tap = r % 9;
  int r2  = r / 9;
  int h   = r2 & 1;
  int r3  = r2 >> 1;
  int ic  = r3 & 511;
  int g   = r3 >> 9;
  int oc  = (g >> 2) * 32 + (g & 3) * 8 + h * 4 + o4;
  w4[gid] = w[((size_t)oc * 512 + ic) * 9 + tap];
}

#define WLOAD(DST, UPTR) do {                                                \
    _Pragma("unroll")                                                        \
    for (int q = 0; q < 36; ++q) (DST)[q] = (UPTR)[q];                       \
  } while (0)

#define CONV_HALF(W, OB) do {                                                \
    _Pragma("unroll")                                                        \
    for (int r = 0; r < 3; ++r)                                              \
    _Pragma("unroll")                                                        \
    for (int kx = 0; kx < 3; ++kx) {                                         \
      _Pragma("unroll")                                                      \
      for (int o = 0; o < 4; ++o) {                                          \
        const float wv = (W)[(r * 3 + kx) * 4 + o];                          \
        _Pragma("unroll")                                                    \
        for (int j = 0; j < 4; ++j)                                          \
          acc[(OB) + o][j] = fmaf(wv, xr[r][j + kx], acc[(OB) + o][j]);      \
      }                                                                      \
    }                                                                        \
  } while (0)

__global__ __launch_bounds__(256, 4) void conv3_kernel(
    const float* __restrict__ x, const float* __restrict__ w4,
    const float* __restrict__ b, float* __restrict__ feat2) {
  const int oct = blockIdx.x;
  const int yt  = blockIdx.y;
  const int n   = blockIdx.z;
  const int t   = threadIdx.x;
  const int wid  = __builtin_amdgcn_readfirstlane(t >> 6);
  const int lane = t & 63;
  const int lrow = lane >> 4;
  const int lcol = (lane & 15) << 2;
  const int y0 = yt << 2;

  __shared__ float xs[2][ICL * 6 * 68];

  float acc[8][4];
#pragma unroll
  for (int o = 0; o < 8; ++o)
#pragma unroll
    for (int j = 0; j < 4; ++j) acc[o][j] = 0.f;

  const float* xb = x + (size_t)n * CIN * NPIX;
  const float* __restrict__ wq = w4 + (size_t)(oct * 4 + wid) * (512 * 72);

  int  goff[NSLOT];
  int  laddr[NSLOT];
  bool val[NSLOT];
#pragma unroll
  for (int k = 0; k < NSLOT; ++k) {
    int s   = t + (k << 8);
    int icl = s / 396;
    int rem = s - icl * 396;
    int row = rem / 66;
    int c   = rem - row * 66;
    int yy = y0 - 1 + row;
    int xx = c - 1;
    bool act = (k < NSLOT - 1) || (t < 96);
    val[k]  = act && ((unsigned)yy < 64u) && ((unsigned)xx < 64u);
    goff[k] = icl * NPIX + yy * 64 + xx;
    laddr[k] = icl * 408 + row * 68 + c;
  }

  {
    float v[NSLOT];
#pragma unroll
    for (int k = 0; k < NSLOT; ++k) v[k] = val[k] ? xb[goff[k]] : 0.f;
#pragma unroll
    for (int k = 0; k < NSLOT; ++k)
      if (k < NSLOT - 1 || t < 96) xs[0][laddr[k]] = v[k];
  }

  float wbA[36], wbB[36];
  WLOAD(wbA, wq);

  for (int cch = 0; cch < 64; ++cch) {
    const int cur = cch & 1;
    float rn[NSLOT];
    if (cch < 63) {
      const float* xn = xb + (size_t)(cch + 1) * (ICL * NPIX);
#pragma unroll
      for (int k = 0; k < NSLOT; ++k) rn[k] = val[k] ? xn[goff[k]] : 0.f;
    }
    __syncthreads();
#pragma unroll 1
    for (int icl = 0; icl < ICL; ++icl) {
      const int u0 = (cch << 4) + (icl << 1);
      const float* xp = &xs[cur][icl * 408 + lrow * 68 + lcol];
      float4 a0 = *(const float4*)(xp);
      float2 b0 = *(const float2*)(xp + 4);
      float4 a1 = *(const float4*)(xp + 68);
      float2 b1 = *(const float2*)(xp + 72);
      float4 a2 = *(const float4*)(xp + 136);
      float2 b2 = *(const float2*)(xp + 140);
      float xr[3][6] = {{a0.x, a0.y, a0.z, a0.w, b0.x, b0.y},
                        {a1.x, a1.y, a1.z, a1.w, b1.x, b1.y},
                        {a2.x, a2.y, a2.z, a2.w, b2.x, b2.y}};
      WLOAD(wbB, wq + (size_t)(u0 + 1) * 36);
      CONV_HALF(wbA, 0);
      {
        const int un = (u0 + 2 < 1024) ? (u0 + 2) : 1023;
        WLOAD(wbA, wq + (size_t)un * 36);
      }
      CONV_HALF(wbB, 4);
    }
    if (cch < 63) {
#pragma unroll
      for (int k = 0; k < NSLOT; ++k)
        if (k < NSLOT - 1 || t < 96) xs[cur ^ 1][laddr[k]] = rn[k];
    }
  }

  const float* __restrict__ bs = b + oct * 32 + wid * 8;
  float bias[8];
#pragma unroll
  for (int o = 0; o < 8; ++o) bias[o] = bs[o];
  float* ob = feat2 + ((size_t)n * NPIX + (y0 + lrow) * 64 + lcol) * 512 + oct * 32 + wid * 8;
#pragma unroll
  for (int j = 0; j < 4; ++j) {
    float4 v0, v1;
    v0.x = fmaxf(acc[0][j] + bias[0], 0.f);
    v0.y = fmaxf(acc[1][j] + bias[1], 0.f);
    v0.z = fmaxf(acc[2][j] + bias[2], 0.f);
    v0.w = fmaxf(acc[3][j] + bias[3], 0.f);
    v1.x = fmaxf(acc[4][j] + bias[4], 0.f);
    v1.y = fmaxf(acc[5][j] + bias[5], 0.f);
    v1.z = fmaxf(acc[6][j] + bias[6], 0.f);
    v1.w = fmaxf(acc[7][j] + bias[7], 0.f);
    *(float4*)(ob + (size_t)j * 512)     = v0;
    *(float4*)(ob + (size_t)j * 512 + 4) = v1;
  }
}

// ================= shared tail kernels (unchanged) =================
__global__ __launch_bounds__(256) void conv1_decode_kernel(
    const float* __restrict__ feat2,
    const float* __restrict__ w_loc, const float* __restrict__ b_loc,
    const float* __restrict__ w_score, const float* __restrict__ b_score,
    const int* __restrict__ ih, const int* __restrict__ iw,
    float* __restrict__ out_locs, float* __restrict__ out_scores,
    float* __restrict__ boxes, unsigned* __restrict__ keys,
    unsigned* __restrict__ hist, float* __restrict__ out_anchor) {
#pragma clang fp contract(off)
  const int y  = blockIdx.x, n = blockIdx.y, hf = blockIdx.z;
  const int t = threadIdx.x;
  const int lane = t & 63;
  const int pg = t >> 4;
  const int cg = t & 15;
  __shared__ float fl2[128 * 34];
  __shared__ float wl2[128 * 64];
  float acc[2][4];
#pragma unroll
  for (int i = 0; i < 2; ++i)
#pragma unroll
    for (int j = 0; j < 4; ++j) acc[i][j] = 0.f;

  const float* fb = feat2 + ((size_t)n * NPIX + y * 64 + hf * 32) * 512;
  for (int ch = 0; ch < 512; ch += 128) {
    for (int idx = t; idx < 32 * 128; idx += 256) {
      int p = idx >> 7, ic = idx & 127;
      fl2[ic * 34 + p] = fb[(size_t)p * 512 + ch + ic];
    }
    for (int idx = t; idx < 64 * 128; idx += 256) {
      int c = idx & 63, ic = idx >> 6;
      float v = 0.f;
      if (c < 36) v = w_loc[c * 512 + ch + ic];
      else if (c < 54) v = w_score[(c - 36) * 512 + ch + ic];
      wl2[ic * 64 + c] = v;
    }
    __syncthreads();
#pragma unroll 4
    for (int ic = 0; ic < 128; ++ic) {
      float2 f = *(const float2*)&fl2[ic * 34 + pg * 2];
      float4 w = *(const float4*)&wl2[ic * 64 + cg * 4];
      float fv[2] = {f.x, f.y};
      float wv[4] = {w.x, w.y, w.z, w.w};
#pragma unroll
      for (int i = 0; i < 2; ++i)
#pragma unroll
        for (int j = 0; j < 4; ++j)
          acc[i][j] = fmaf(wv[j], fv[i], acc[i][j]);
    }
    __syncthreads();
  }
#pragma unroll
  for (int j = 0; j < 4; ++j) {
    int c = cg * 4 + j;
    float bias = (c < 36) ? b_loc[c] : (c < 54 ? b_score[c - 36] : 0.f);
#pragma unroll
    for (int i = 0; i < 2; ++i) {
      int pxl = pg * 2 + i;
      float v = acc[i][j] + bias;
      size_t pix0 = (size_t)y * 64 + hf * 32 + pxl;
      if (c < 36) {
        out_locs[((size_t)n * NPIX + pix0) * 36 + c] = v;
        fl2[pxl * 56 + c] = v;
      } else if (c < 54) {
        out_scores[((size_t)n * NPIX + pix0) * 18 + (c - 36)] = v;
        fl2[pxl * 56 + c] = v;
      }
    }
  }
  __syncthreads();
  for (int task = t; task < 288; task += 256) {
    int lpx = task / 9;
    int a   = task - lpx * 9;
    int xq = hf * 32 + lpx, yq = y;
    int i = (yq * 64 + xq) * 9 + a;
    int gid = n * NANCH + i;
    int ri = a / 3, si = a - ri * 3;
    double ratio = (ri == 0) ? 0.5 : (ri == 1 ? 1.0 : 2.0);
    double scl   = (si == 0) ? 8.0 : (si == 1 ? 16.0 : 32.0);
    double hh = 16.0 * scl * sqrt(ratio);
    double ww = 16.0 * scl * sqrt(1.0 / ratio);
    float sx = (float)(xq * 16), sy = (float)(yq * 16);
    float ax1 = (float)(8.0 - ww * 0.5) + sx;
    float ay1 = (float)(8.0 - hh * 0.5) + sy;
    float ax2 = (float)(8.0 + ww * 0.5) + sx;
    float ay2 = (float)(8.0 + hh * 0.5) + sy;
    if (n == 0) {
      *(float4*)(out_anchor + (size_t)i * 4) = make_float4(ax1, ay1, ax2, ay2);
    }
    float l0 = fl2[lpx * 56 + a * 4 + 0];
    float l1 = fl2[lpx * 56 + a * 4 + 1];
    float l2 = fl2[lpx * 56 + a * 4 + 2];
    float l3 = fl2[lpx * 56 + a * 4 + 3];
    float aw = ax2 - ax1, ah = ay2 - ay1;
    float cx = ax1 + 0.5f * aw, cy = ay1 + 0.5f * ah;
    float ctrx = l0 * aw + cx, ctry = l1 * ah + cy;
    float nw = expf(l2) * aw, nh = expf(l3) * ah;
    float x1 = ctrx - 0.5f * nw, y1 = ctry - 0.5f * nh;
    float x2 = ctrx + 0.5f * nw, y2 = ctry + 0.5f * nh;
    float W = (float)iw[0], H = (float)ih[0];
    x1 = fminf(fmaxf(x1, 0.f), W);
    y1 = fminf(fmaxf(y1, 0.f), H);
    x2 = fminf(fmaxf(x2, 0.f), W);
    y2 = fminf(fmaxf(y2, 0.f), H);
    bool valid = ((x2 - x1) >= 16.f) && ((y2 - y1) >= 16.f);
    float s0 = fl2[lpx * 56 + 36 + a * 2];
    float s1 = fl2[lpx * 56 + 36 + a * 2 + 1];
    float mx = fmaxf(s0, s1);
    float e0 = expf(s0 - mx), e1 = expf(s1 - mx);
    float fg = e1 / (e0 + e1);
    float sc = valid ? fg : -1e9f;
    unsigned bb = __float_as_uint(sc);
    unsigned v = (bb & 0x80000000u) ? ~bb : (bb | 0x80000000u);
    keys[gid] = v;
    *(float4*)(boxes + (size_t)gid * 4) = make_float4(x1, y1, x2, y2);
    unsigned bin = v >> 16;
    unsigned tix = ((bin & 255u) << 8) | (bin >> 8);
    unsigned long long mv = __ballot(!valid);
    if (!valid) {
      int leader = __ffsll(mv) - 1;
      if (lane == leader)
        atomicAdd(&hist[(size_t)n * 65536 + tix], (unsigned)__popcll(mv));
    } else {
      atomicAdd(&hist[(size_t)n * 65536 + tix], 1u);
    }
  }
}

__global__ __launch_bounds__(256) void compact_kernel(
    const unsigned* __restrict__ keys, const unsigned* __restrict__ hist,
    unsigned* __restrict__ cnt, unsigned long long* __restrict__ cand) {
  int t = threadIdx.x;
  int gid = blockIdx.x * 256 + t;
  int lane = t & 63;
  int n = (blockIdx.x << 8) / NANCH;
  int i = gid - n * NANCH;
  const unsigned* h = hist + (size_t)n * 65536;
  __shared__ unsigned csum[256];
  __shared__ unsigned fine[256];
  __shared__ unsigned csel, cumsh, cutsh;
  unsigned s = 0;
  for (int low = 0; low < 256; ++low) s += h[low * 256 + t];
  csum[t] = s;
  __syncthreads();
  if (t == 0) {
    unsigned cum = 0;
    int c = 255;
    for (; c > 0; --c) {
      if (cum + csum[c] >= PREN) break;
      cum += csum[c];
    }
    csel = (unsigned)c;
    cumsh = cum;
  }
  __syncthreads();
  int c = (int)csel;
  fine[t] = h[t * 256 + c];
  __syncthreads();
  if (t == 0) {
    unsigned cum = cumsh;
    unsigned P = (unsigned)(c << 8);
    for (int low = 255; low >= 0; --low) {
      cum += fine[low];
      if (cum >= PREN) { P = (unsigned)((c << 8) | low); break; }
    }
    cutsh = P;
  }
  __syncthreads();
  unsigned P = cutsh;
  unsigned v = keys[gid];
  bool take = (v >> 16) >= P;
  unsigned long long m = __ballot(take);
  if (take) {
    int leader = __ffsll(m) - 1;
    int tot = __popcll(m);
    int pre = __popcll(m & ((lane == 0) ? 0ull : (~0ull >> (64 - lane))));
    unsigned base = 0;
    if (lane == leader) base = atomicAdd(&cnt[n], (unsigned)tot);
    base = __shfl(base, leader);
    cand[(size_t)n * NANCH + base + pre] =
        ((unsigned long long)v << 32) | (unsigned)(~i);
  }
}

__global__ __launch_bounds__(256) void rank2_kernel(
    const unsigned long long* __restrict__ cand, const unsigned* __restrict__ cnt,
    const float* __restrict__ boxes, float* __restrict__ sboxes) {
  int n = blockIdx.y;
  int C = (int)cnt[n];
  if (blockIdx.x * 256 >= C) return;
  int t = threadIdx.x;
  int i = blockIdx.x * 256 + t;
  const unsigned long long* cb = cand + (size_t)n * NANCH;
  unsigned long long Ki = (i < C) ? cb[i] : 0ull;
  __shared__ unsigned long long tile[256];
  int rank = 0;
  for (int t0 = 0; t0 < C; t0 += 256) {
    __syncthreads();
    int j = t0 + t;
    tile[t] = (j < C) ? cb[j] : 0ull;
    __syncthreads();
#pragma unroll 16
    for (int jj = 0; jj < 256; ++jj)
      rank += (tile[jj] > Ki) ? 1 : 0;
  }
  if (i < C && rank < PREN) {
    unsigned orig = ~(unsigned)(Ki & 0xffffffffull);
    float4 bb = *(const float4*)(boxes + ((size_t)n * NANCH + orig) * 4);
    *(float4*)(sboxes + ((size_t)n * PREN + rank) * 4) = bb;
  }
}

__global__ __launch_bounds__(256) void iou_kernel(
    const float* __restrict__ sboxes, unsigned long long* __restrict__ sup) {
#pragma clang fp contract(off)
  int n = blockIdx.y, i = blockIdx.x;
  const float* B = sboxes + (size_t)n * PREN * 4;
  float4 bi = *(const float4*)(B + (size_t)i * 4);
  float area_i = (bi.z - bi.x) * (bi.w - bi.y);
  int lane = threadIdx.x & 63, wv = threadIdx.x >> 6;
  unsigned long long* row = sup + ((size_t)n * PREN + i) * 64;
  for (int w0 = wv; w0 < 64; w0 += 4) {
    int j = w0 * 64 + lane;
    bool p = false;
    if (j < PREN) {
      float4 bj = *(const float4*)(B + (size_t)j * 4);
      float area_j = (bj.z - bj.x) * (bj.w - bj.y);
      float x1 = fmaxf(bi.x, bj.x), y1 = fmaxf(bi.y, bj.y);
      float x2 = fminf(bi.z, bj.z), y2 = fminf(bi.w, bj.w);
      float inter = fmaxf(x2 - x1, 0.f) * fmaxf(y2 - y1, 0.f);
      float iou = inter / (area_i + area_j - inter + 1e-9f);
      p = iou > 0.7f;
    }
    unsigned long long m = __ballot(p);
    if (lane == 0) row[w0] = m;
  }
}

__global__ __launch_bounds__(64) void nms_kernel(
    const unsigned long long* __restrict__ sup, const float* __restrict__ sboxes,
    float* __restrict__ rois, float* __restrict__ ridx) {
  int n = blockIdx.x;
  int lane = threadIdx.x;
  const unsigned long long* S = sup + (size_t)n * PREN * 64;
  unsigned long long buf[64];
#pragma unroll
  for (int bq = 0; bq < 64; ++bq) buf[bq] = S[(size_t)bq * 64 + lane];
  unsigned long long keep = (lane < 46) ? ~0ull
                          : (lane == 46 ? ((1ull << 56) - 1ull) : 0ull);
  for (int w = 0; w < 47; ++w) {
    unsigned long long kw = __shfl(keep, w);
    unsigned long long gtmask = (lane > w) ? ~0ull : 0ull;
#pragma unroll
    for (int bq = 0; bq < 64; ++bq) {
      const int i = w * 64 + bq;
      unsigned long long r = buf[bq];
      if (i + 64 < PREN) buf[bq] = S[(size_t)(i + 64) * 64 + lane];
      unsigned long long rw = __shfl(r, w);
      unsigned long long amask = ((kw >> bq) & 1ull) ? ~0ull : 0ull;
      const unsigned long long fmask = (bq == 63) ? 0ull : ~((2ull << bq) - 1ull);
      kw &= ~(rw & fmask & amask);
      keep &= ~(r & gtmask & amask);
    }
    keep = (lane == w) ? kw : keep;
  }
  int cnt = __popcll(keep);
  int scn = cnt;
  for (int d = 1; d < 64; d <<= 1) {
    int v = __shfl_up(scn, d);
    if (lane >= d) scn += v;
  }
  int excl = scn - cnt;
  int total = __shfl(scn, 63);
  const float* SB = sboxes + (size_t)n * PREN * 4;
  unsigned long long kk = keep;
  int p = excl;
  while (kk) {
    int bpos = __ffsll(kk) - 1;
    kk &= kk - 1ull;
    if (p < POSTN) {
      float4 bb = *(const float4*)(SB + (size_t)(lane * 64 + bpos) * 4);
      *(float4*)(rois + ((size_t)n * POSTN + p) * 4) = bb;
    }
    ++p;
  }
  if (lane == 0) {
    float4 b0 = *(const float4*)SB;
    for (int q = total; q < POSTN; ++q)
      *(float4*)(rois + ((size_t)n * POSTN + q) * 4) = b0;
  }
  for (int q = lane; q < POSTN; q += 64) ridx[n * POSTN + q] = (float)n;
}

extern "C" void kernel_launch(void* const* d_in, const int* in_sizes, int n_in,
                              void* d_out, int out_size, void* d_ws, size_t ws_size,
                              hipStream_t stream) {
  const float* x       = (const float*)d_in[0];
  const float* w_conv  = (const float*)d_in[1];
  const float* b_conv  = (const float*)d_in[2];
  const float* w_score = (const float*)d_in[3];
  const float* b_score = (const float*)d_in[4];
  const float* w_loc   = (const float*)d_in[5];
  const float* b_loc   = (const float*)d_in[6];
  const int*   img_h   = (const int*)d_in[7];
  const int*   img_w   = (const int*)d_in[8];

  float* out        = (float*)d_out;
  float* out_locs   = out;
  float* out_scores = out + 589824;
  float* out_rois   = out + 884736;
  float* out_ridx   = out + 889536;
  float* out_anchor = out + 890736;

  const size_t NEED = 76546112;   // feat2 33.55M | wt 9.44M | xt 33.55M | zpage 64B
  if (ws_size >= NEED) {
    // ---- MFMA path (f16x2 split, B->reg, A dbuf, 1 barrier/icc) ----
    float* feat2 = (float*)d_ws;                                   // 33,554,432 B
    short* wth   = (short*)((char*)d_ws + 33554432);               //  4,718,592 B
    short* wtl   = wth + 2359296;                                  //  4,718,592 B
    short* xth   = (short*)((char*)d_ws + 42991616);               // 16,777,216 B
    short* xtl   = xth + 8388608;                                  // 16,777,216 B
    char*  zpage = (char*)d_ws + 76546048;                         //         64 B
    // post-conv aliases: boxes region over wt (dead), hist/cand over xt (dead)
    float* boxes = (float*)wth;                                    // 2,359,296 B
    unsigned* keys = (unsigned*)(boxes + 589824);
    float* sboxes  = (float*)(keys + 147456);
    unsigned long long* sup = (unsigned long long*)(sboxes + 48000);
    unsigned* hist = (unsigned*)xth;
    unsigned* cnt  = hist + 262148;
    unsigned long long* cand = (unsigned long long*)(hist + 262160);

    xform_w_kernel<<<512, 256, 0, stream>>>(w_conv, wth, wtl, (unsigned*)zpage);
    xform_x_kernel<<<dim3(64, 4), 256, 0, stream>>>(x, xth, xtl);
    conv3_mfma<<<dim3(32, 4, 4), 256, 0, stream>>>(xth, xtl, wth, wtl, b_conv,
                                                   zpage, feat2);
    zero_hist_kernel<<<1025, 256, 0, stream>>>(hist);
    conv1_decode_kernel<<<dim3(64, 4, 2), 256, 0, stream>>>(
        feat2, w_loc, b_loc, w_score, b_score, img_h, img_w,
        out_locs, out_scores, boxes, keys, hist, out_anchor);
    compact_kernel<<<576, 256, 0, stream>>>(keys, hist, cnt, cand);
    rank2_kernel<<<dim3(144, 4), 256, 0, stream>>>(cand, cnt, boxes, sboxes);
    iou_kernel<<<dim3(PREN, 4), 256, 0, stream>>>(sboxes, sup);
    nms_kernel<<<4, 64, 0, stream>>>(sup, sboxes, out_rois, out_ridx);
  } else {
    // ---- fallback: previous fp32 pipeline (ws too small for MFMA path) ----
    float* feat2 = (float*)d_ws;
    float* A     = feat2 + (size_t)8388608;
    float* w4    = A;
    float* boxes = A;
    unsigned* keys = (unsigned*)(boxes + 589824);
    float* sboxes  = (float*)(keys + 147456);
    unsigned long long* sup = (unsigned long long*)(sboxes + 48000);
    unsigned* hist = (unsigned*)(A + 2359296);
    unsigned* cnt  = hist + 262148;
    unsigned long long* cand = (unsigned long long*)(hist + 262160);

    reshape_w_kernel<<<9216, 256, 0, stream>>>(w_conv, w4, hist);
    conv3_kernel<<<dim3(16, 16, 4), 256, 0, stream>>>(x, w4, b_conv, feat2);
    conv1_decode_kernel<<<dim3(64, 4, 2), 256, 0, stream>>>(
        feat2, w_loc, b_loc, w_score, b_score, img_h, img_w,
        out_locs, out_scores, boxes, keys, hist, out_anchor);
    compact_kernel<<<576, 256, 0, stream>>>(keys, hist, cnt, cand);
    rank2_kernel<<<dim3(144, 4), 256, 0, stream>>>(cand, cnt, boxes, sboxes);
    iou_kernel<<<dim3(PREN, 4), 256, 0, stream>>>(sboxes, sup);
    nms_kernel<<<4, 64, 0, stream>>>(sup, sboxes, out_rois, out_ridx);
  }
}

// Round 9
// 975.552 us; speedup vs baseline: 1.1820x; 1.1820x over previous
//
#include <hip/hip_runtime.h>
#include <cstdint>
#include <cmath>

#define HW 64
#define NPIX 4096          // 64*64
#define CIN 512
#define NANCH 36864        // 4096*9
#define PREN 3000
#define POSTN 300
#define ICL 8
#define NSLOT 13           // ceil(8*6*66 / 256), last slot: 96 threads

typedef _Float16 h8v __attribute__((ext_vector_type(8)));
typedef float f16v __attribute__((ext_vector_type(16)));

#define AS1 __attribute__((address_space(1)))
#define AS3 __attribute__((address_space(3)))

__device__ __forceinline__ void gl16(const void* g, void* l) {
  __builtin_amdgcn_global_load_lds((const AS1 void*)g, (AS3 void*)l, 16, 0, 0);
}

// f16 two-term split: f = h + l with |f-h-l| <= |f|*2^-22 (f pre-scaled so
// both h and l stay in f16 normal range; scaling by 2^k is exact).
__device__ __forceinline__ void f16_split(float f, short& h, short& l) {
  _Float16 hh = (_Float16)f;
  float hf = (float)hh;
  _Float16 ll = (_Float16)(f - hf);
  h = __builtin_bit_cast(short, hh);
  l = __builtin_bit_cast(short, ll);
}

// ==================== MFMA PATH: f16x2-split conv ====================

// ---- w (512oc,512ic,3,3) fp32 -> wth/wtl fragment-major f16 hi/lo, x128 ----
// Layout (shorts): [tap][icc][kh][lh][oc 0..511][8 ic]
__global__ __launch_bounds__(256) void xform_w_kernel(
    const float* __restrict__ w, short* __restrict__ wth,
    short* __restrict__ wtl, unsigned* __restrict__ zp) {
  const int oc = blockIdx.x;
  const int t = threadIdx.x;
  __shared__ float ws_[4608];
  const float* wr = w + (size_t)oc * 4608;
  for (int i = t; i < 4608; i += 256) ws_[i] = wr[i];
  __syncthreads();
  for (int c = t; c < 576; c += 256) {
    int tap = c / 64;
    int g = c - tap * 64;            // ic-group of 8: ic = g*8 .. g*8+7
    int icc = g >> 2;
    int kh = (g >> 1) & 1;
    int lhh = g & 1;
    h8v hv, lv;
    short* hp = (short*)&hv;
    short* lp = (short*)&lv;
#pragma unroll
    for (int j = 0; j < 8; ++j) {
      short hh, ll;
      f16_split(ws_[(g * 8 + j) * 9 + tap] * 128.0f, hh, ll);
      hp[j] = hh; lp[j] = ll;
    }
    long o = (((((long)tap * 16 + icc) * 2 + kh) * 2 + lhh) * 512 + oc) * 8;
    *(h8v*)(wth + o) = hv;
    *(h8v*)(wtl + o) = lv;
  }
  if (oc == 0 && t < 16) zp[t] = 0u;   // zero-page for halo redirect
}

// ---- x NCHW fp32 -> xth/xtl [n][y][x][ic] f16 hi/lo (NHWC), x2048 ----
__global__ __launch_bounds__(256) void xform_x_kernel(
    const float* __restrict__ x, short* __restrict__ xth,
    short* __restrict__ xtl) {
  const int yb = blockIdx.x;   // 0..63
  const int n = blockIdx.y;
  const int t = threadIdx.x;
  __shared__ float xs[64 * 65];
  const float* xr = x + ((size_t)n * 512) * 4096 + yb * 64;
  short* oh = xth + ((size_t)n * 4096 + yb * 64) * 512;
  short* ol = xtl + ((size_t)n * 4096 + yb * 64) * 512;
  for (int icb = 0; icb < 8; ++icb) {
    if (icb) __syncthreads();
#pragma unroll
    for (int q = 0; q < 16; ++q) {
      int idx = q * 256 + t;
      int icl = idx >> 6, xc = idx & 63;
      xs[icl * 65 + xc] = xr[(size_t)(icb * 64 + icl) * 4096 + xc];
    }
    __syncthreads();
#pragma unroll
    for (int q = 0; q < 2; ++q) {
      int c = q * 256 + t;
      int xc = c >> 3, icg = c & 7;
      h8v hv, lv;
      short* hp = (short*)&hv;
      short* lp = (short*)&lv;
#pragma unroll
      for (int j = 0; j < 8; ++j) {
        short hh, ll;
        f16_split(xs[(icg * 8 + j) * 65 + xc] * 2048.0f, hh, ll);
        hp[j] = hh; lp[j] = ll;
      }
      size_t o = (size_t)xc * 512 + icb * 64 + icg * 8;
      *(h8v*)(oh + o) = hv;
      *(h8v*)(ol + o) = lv;
    }
  }
}

// ---- 3x3 conv via implicit GEMM on matrix cores, f16x2 split (3 MFMA) ----
// grid (32 ypair-raw, 4, 4n), 256 thr = 4 waves; block tile 2rows x 64cols x 128oc.
// A-slab: LDS, DOUBLE-buffered [abuf][hilo][4row x 68col][32ic] (69632 B).
// B: global->VGPR in fragment layout (L2-resident), prefetched 1 tap ahead
// (single Bcur/Bnxt pair, R7's proven 112-VGPR shape — NO A-frag pipeline,
// R8's FragA ping-pong spilled to scratch: WRITE_SIZE 32->392 MB).
// R9: next-icc A restage issued at TAP 0 into buf^1 -> gl16s land during the
// 9-tap group -> ONE barrier per icc with ~free drain (R7 had two, second
// drained freshly-issued gl16s = full L2 latency x 16 boundaries).
// A-fragment reads stay inline in the MFMA body (registers minimal).
// Result scaled 2^18; chunked S-drain per icc (bit-identical to R3 order).
__global__ __launch_bounds__(256, 2) void conv3_mfma(
    const short* __restrict__ xth, const short* __restrict__ xtl,
    const short* __restrict__ wth, const short* __restrict__ wtl,
    const float* __restrict__ bconv, const char* __restrict__ zpage,
    float* __restrict__ feat2) {
  const int t = threadIdx.x;
  const int lane = t & 63;
  const int wid = __builtin_amdgcn_readfirstlane(t >> 6);
  const int l31 = lane & 31, lh = lane >> 5;
  const int wm = wid >> 1, wn = wid & 1;

  // XCD-aware swizzle: each XCD (bx%8) owns one 128-oc weight panel (L2-fit).
  const int bx = blockIdx.x, by = blockIdx.y, n = blockIdx.z;
  const int k8 = bx & 7;
  const int ocb = k8 & 3;
  const int yp = (k8 >> 2) * 16 + (bx >> 3) * 4 + by;  // 0..31
  const int y0 = yp * 2;
  const int ocbase = ocb * 128;

  __shared__ short As[2][2][272 * 32];   // [abuf][hilo][...] 69632 B
  char* const asb = (char*)&As[0][0][0];

  // ---- A staging descriptors: 34x 1KB blocks over 4 waves ----
  const char* asrc[9]; int adst[9]; int astep[9];
  {
    const char* xs0 = (const char*)xth;
    const char* xs1 = (const char*)xtl;
#pragma unroll
    for (int k = 0; k < 9; ++k) {
      int bq = wid + 4 * k;
      if (bq < 34) {
        int hl = (bq >= 17) ? 1 : 0;
        int blk = bq - hl * 17;
        int e = blk * 16 + (lane >> 2);
        int slot = lane & 3;
        int r = e / 68;
        int cp = e - r * 68;
        int y = y0 - 1 + r;
        int c = cp - 1;
        bool valid = (cp >= 1) && (cp <= 64) && (y >= 0) && (y < 64);
        int ss = slot ^ ((e >> 1) & 3);                 // source pre-swizzle
        long off = ((((long)n * 64 + y) * 64 + c) * 512 + ss * 8) * 2;
        asrc[k] = valid ? ((hl ? xs1 : xs0) + off) : (const char*)zpage;
        astep[k] = valid ? 64 : 0;                      // 32 ic * 2B per icc
        adst[k] = hl * 17408 + blk * 1024;
      }
    }
  }

  // ---- B fragment global base: lane-constant offset (shorts) ----
  const long lane_b = (long)lh * 4096 + (long)(ocbase + wn * 64 + l31) * 8;

  struct FragB { h8v h[2][2], l[2][2]; };   // [kh][fn]

#define READ_Bg(F, TAP, ICC) do {                                            \
    long sb_ = ((long)(TAP) * 16 + (ICC)) * 16384 + lane_b;                  \
    _Pragma("unroll")                                                        \
    for (int kh_ = 0; kh_ < 2; ++kh_)                                        \
      _Pragma("unroll")                                                      \
      for (int fn_ = 0; fn_ < 2; ++fn_) {                                    \
        long o_ = sb_ + kh_ * 8192 + fn_ * 256;                              \
        (F).h[kh_][fn_] = *(const h8v*)(wth + o_);                           \
        (F).l[kh_][fn_] = *(const h8v*)(wtl + o_);                           \
      }                                                                      \
  } while (0)

#define COMP_AE(AE, TAP) do {                                                 \
    int dy_ = (TAP) / 3, dx_ = (TAP) - dy_ * 3;                               \
    _Pragma("unroll")                                                         \
    for (int fm_ = 0; fm_ < 2; ++fm_) {                                       \
      int e_ = (wm + dy_) * 68 + fm_ * 32 + l31 + dx_;                        \
      (AE)[fm_] = e_ * 64 + ((lh ^ ((e_ >> 1) & 3)) << 4);                    \
    }                                                                         \
  } while (0)

  // per kh: read 4 A granules from LDS (inline), then 12 MFMAs (R3 order).
#define TAP_MFMA(BC, AB) do {                                                 \
    _Pragma("unroll")                                                         \
    for (int kh_ = 0; kh_ < 2; ++kh_) {                                       \
      h8v Ah_[2], Al_[2];                                                     \
      _Pragma("unroll")                                                       \
      for (int fm_ = 0; fm_ < 2; ++fm_) {                                     \
        int a0_ = ae[fm_] ^ (kh_ << 5);                                       \
        Ah_[fm_] = *(const h8v*)((AB) + a0_);                                 \
        Al_[fm_] = *(const h8v*)((AB) + 17408 + a0_);                         \
      }                                                                       \
      _Pragma("unroll")                                                       \
      for (int fm_ = 0; fm_ < 2; ++fm_)                                       \
        _Pragma("unroll")                                                     \
        for (int fn_ = 0; fn_ < 2; ++fn_)                                     \
          acc[fm_][fn_] = __builtin_amdgcn_mfma_f32_32x32x16_f16(             \
              Ah_[fm_], (BC).h[kh_][fn_], acc[fm_][fn_], 0, 0, 0);            \
      _Pragma("unroll")                                                       \
      for (int fm_ = 0; fm_ < 2; ++fm_)                                       \
        _Pragma("unroll")                                                     \
        for (int fn_ = 0; fn_ < 2; ++fn_)                                     \
          acc[fm_][fn_] = __builtin_amdgcn_mfma_f32_32x32x16_f16(             \
              Al_[fm_], (BC).h[kh_][fn_], acc[fm_][fn_], 0, 0, 0);            \
      _Pragma("unroll")                                                       \
      for (int fm_ = 0; fm_ < 2; ++fm_)                                       \
        _Pragma("unroll")                                                     \
        for (int fn_ = 0; fn_ < 2; ++fn_)                                     \
          acc[fm_][fn_] = __builtin_amdgcn_mfma_f32_32x32x16_f16(             \
              Ah_[fm_], (BC).l[kh_][fn_], acc[fm_][fn_], 0, 0, 0);            \
    }                                                                         \
  } while (0)

  f16v acc[2][2];   // per-icc chunk accumulator (MFMA C)
  f16v S[2][2];     // running sum across chunks
#pragma unroll
  for (int i = 0; i < 2; ++i)
#pragma unroll
    for (int j = 0; j < 2; ++j)
#pragma unroll
      for (int r = 0; r < 16; ++r) { acc[i][j][r] = 0.f; S[i][j][r] = 0.f; }

  // prologue: A(icc=0) -> buf0; B(0,0) -> regs
#pragma unroll
  for (int k = 0; k < 9; ++k) {
    int bq = wid + 4 * k;
    if (bq < 34) gl16(asrc[k], asb + adst[k]);
  }
  FragB Bcur, Bnxt;
  READ_Bg(Bcur, 0, 0);
  __syncthreads();
  int ae[2];
  int acur = 0;

#pragma unroll 1
  for (int icc = 0; icc < 16; ++icc) {
    char* const abase = asb + acur * 34816;
    char* const abnxt = asb + (acur ^ 1) * 34816;
#pragma unroll
    for (int tap = 0; tap < 9; ++tap) {
      const int tapN = (tap < 8) ? tap + 1 : 0;
      const int iccN = (tap < 8) ? icc : ((icc < 15) ? icc + 1 : 15);
      READ_Bg(Bnxt, tapN, iccN);            // per-wave B prefetch (1 ahead)
      if (tap == 0 && icc < 15) {           // stage NEXT icc A -> other buf
#pragma unroll
        for (int k = 0; k < 9; ++k) {
          int bq = wid + 4 * k;
          if (bq < 34) { asrc[k] += astep[k]; gl16(asrc[k], abnxt + adst[k]); }
        }
      }
      COMP_AE(ae, tap);
      TAP_MFMA(Bcur, abase);
      Bcur = Bnxt;
    }
    // drain chunk accumulator into S (same position as R3 -> bit-exact)
#pragma unroll
    for (int fm = 0; fm < 2; ++fm)
#pragma unroll
      for (int fn = 0; fn < 2; ++fn)
#pragma unroll
        for (int r = 0; r < 16; ++r) {
          S[fm][fn][r] += acc[fm][fn][r];
          acc[fm][fn][r] = 0.f;
        }
    __syncthreads();      // reads of abase done; gl16s (9 taps old) ~free
    acur ^= 1;
  }

#undef READ_Bg
#undef COMP_AE
#undef TAP_MFMA

  // ---- epilogue: unscale + bias + ReLU -> feat2 NHWC ----
  const float OS = 1.0f / 262144.0f;       // 2^-18 (x*2^11 * w*2^7)
  const float* bb = bconv + ocbase + wn * 64;
#pragma unroll
  for (int fn = 0; fn < 2; ++fn) {
    const float bias = bb[fn * 32 + l31];
#pragma unroll
    for (int fm = 0; fm < 2; ++fm) {
      float* op = feat2 + (((long)n * 4096 + (y0 + wm) * 64 + fm * 32) * 512)
                + ocbase + wn * 64 + fn * 32 + l31;
#pragma unroll
      for (int r = 0; r < 16; ++r) {
        int m = (r & 3) + 8 * (r >> 2) + 4 * lh;
        op[(long)m * 512] = fmaxf(S[fm][fn][r] * OS + bias, 0.f);
      }
    }
  }
}

__global__ __launch_bounds__(256) void zero_hist_kernel(unsigned* __restrict__ h) {
  int i = blockIdx.x * 256 + threadIdx.x;
  if (i < 262160) h[i] = 0u;
}

// ============== OLD PATH (fallback if ws_size is too small) ==============
__global__ __launch_bounds__(256) void reshape_w_kernel(
    const float* __restrict__ w, float* __restrict__ w4,
    unsigned* __restrict__ histz) {
  int gid = blockIdx.x * 256 + threadIdx.x;
  if (gid < 262160) histz[gid] = 0;
  if (gid >= 512 * 512 * 9) return;
  int o4  = gid & 3;
  int r   = gid >> 2;
  int tap = r % 9;
  int r2  = r / 9;
  int h   = r2 & 1;
  int r3  = r2 >> 1;
  int ic  = r3 & 511;
  int g   = r3 >> 9;
  int oc  = (g >> 2) * 32 + (g & 3) * 8 + h * 4 + o4;
  w4[gid] = w[((size_t)oc * 512 + ic) * 9 + tap];
}

#define WLOAD(DST, UPTR) do {                                                \
    _Pragma("unroll")                                                        \
    for (int q = 0; q < 36; ++q) (DST)[q] = (UPTR)[q];                       \
  } while (0)

#define CONV_HALF(W, OB) do {                                                \
    _Pragma("unroll")                                                        \
    for (int r = 0; r < 3; ++r)                                              \
    _Pragma("unroll")                                                        \
    for (int kx = 0; kx < 3; ++kx) {                                         \
      _Pragma("unroll")                                                      \
      for (int o = 0; o < 4; ++o) {                                          \
        const float wv = (W)[(r * 3 + kx) * 4 + o];                          \
        _Pragma("unroll")                                                    \
        for (int j = 0; j < 4; ++j)                                          \
          acc[(OB) + o][j] = fmaf(wv, xr[r][j + kx], acc[(OB) + o][j]);      \
      }                                                                      \
    }                                                                        \
  } while (0)

__global__ __launch_bounds__(256, 4) void conv3_kernel(
    const float* __restrict__ x, const float* __restrict__ w4,
    const float* __restrict__ b, float* __restrict__ feat2) {
  const int oct = blockIdx.x;
  const int yt  = blockIdx.y;
  const int n   = blockIdx.z;
  const int t   = threadIdx.x;
  const int wid  = __builtin_amdgcn_readfirstlane(t >> 6);
  const int lane = t & 63;
  const int lrow = lane >> 4;
  const int lcol = (lane & 15) << 2;
  const int y0 = yt << 2;

  __shared__ float xs[2][ICL * 6 * 68];

  float acc[8][4];
#pragma unroll
  for (int o = 0; o < 8; ++o)
#pragma unroll
    for (int j = 0; j < 4; ++j) acc[o][j] = 0.f;

  const float* xb = x + (size_t)n * CIN * NPIX;
  const float* __restrict__ wq = w4 + (size_t)(oct * 4 + wid) * (512 * 72);

  int  goff[NSLOT];
  int  laddr[NSLOT];
  bool val[NSLOT];
#pragma unroll
  for (int k = 0; k < NSLOT; ++k) {
    int s   = t + (k << 8);
    int icl = s / 396;
    int rem = s - icl * 396;
    int row = rem / 66;
    int c   = rem - row * 66;
    int yy = y0 - 1 + row;
    int xx = c - 1;
    bool act = (k < NSLOT - 1) || (t < 96);
    val[k]  = act && ((unsigned)yy < 64u) && ((unsigned)xx < 64u);
    goff[k] = icl * NPIX + yy * 64 + xx;
    laddr[k] = icl * 408 + row * 68 + c;
  }

  {
    float v[NSLOT];
#pragma unroll
    for (int k = 0; k < NSLOT; ++k) v[k] = val[k] ? xb[goff[k]] : 0.f;
#pragma unroll
    for (int k = 0; k < NSLOT; ++k)
      if (k < NSLOT - 1 || t < 96) xs[0][laddr[k]] = v[k];
  }

  float wbA[36], wbB[36];
  WLOAD(wbA, wq);

  for (int cch = 0; cch < 64; ++cch) {
    const int cur = cch & 1;
    float rn[NSLOT];
    if (cch < 63) {
      const float* xn = xb + (size_t)(cch + 1) * (ICL * NPIX);
#pragma unroll
      for (int k = 0; k < NSLOT; ++k) rn[k] = val[k] ? xn[goff[k]] : 0.f;
    }
    __syncthreads();
#pragma unroll 1
    for (int icl = 0; icl < ICL; ++icl) {
      const int u0 = (cch << 4) + (icl << 1);
      const float* xp = &xs[cur][icl * 408 + lrow * 68 + lcol];
      float4 a0 = *(const float4*)(xp);
      float2 b0 = *(const float2*)(xp + 4);
      float4 a1 = *(const float4*)(xp + 68);
      float2 b1 = *(const float2*)(xp + 72);
      float4 a2 = *(const float4*)(xp + 136);
      float2 b2 = *(const float2*)(xp + 140);
      float xr[3][6] = {{a0.x, a0.y, a0.z, a0.w, b0.x, b0.y},
                        {a1.x, a1.y, a1.z, a1.w, b1.x, b1.y},
                        {a2.x, a2.y, a2.z, a2.w, b2.x, b2.y}};
      WLOAD(wbB, wq + (size_t)(u0 + 1) * 36);
      CONV_HALF(wbA, 0);
      {
        const int un = (u0 + 2 < 1024) ? (u0 + 2) : 1023;
        WLOAD(wbA, wq + (size_t)un * 36);
      }
      CONV_HALF(wbB, 4);
    }
    if (cch < 63) {
#pragma unroll
      for (int k = 0; k < NSLOT; ++k)
        if (k < NSLOT - 1 || t < 96) xs[cur ^ 1][laddr[k]] = rn[k];
    }
  }

  const float* __restrict__ bs = b + oct * 32 + wid * 8;
  float bias[8];
#pragma unroll
  for (int o = 0; o < 8; ++o) bias[o] = bs[o];
  float* ob = feat2 + ((size_t)n * NPIX + (y0 + lrow) * 64 + lcol) * 512 + oct * 32 + wid * 8;
#pragma unroll
  for (int j = 0; j < 4; ++j) {
    float4 v0, v1;
    v0.x = fmaxf(acc[0][j] + bias[0], 0.f);
    v0.y = fmaxf(acc[1][j] + bias[1], 0.f);
    v0.z = fmaxf(acc[2][j] + bias[2], 0.f);
    v0.w = fmaxf(acc[3][j] + bias[3], 0.f);
    v1.x = fmaxf(acc[4][j] + bias[4], 0.f);
    v1.y = fmaxf(acc[5][j] + bias[5], 0.f);
    v1.z = fmaxf(acc[6][j] + bias[6], 0.f);
    v1.w = fmaxf(acc[7][j] + bias[7], 0.f);
    *(float4*)(ob + (size_t)j * 512)     = v0;
    *(float4*)(ob + (size_t)j * 512 + 4) = v1;
  }
}

// ================= shared tail kernels (unchanged) =================
__global__ __launch_bounds__(256) void conv1_decode_kernel(
    const float* __restrict__ feat2,
    const float* __restrict__ w_loc, const float* __restrict__ b_loc,
    const float* __restrict__ w_score, const float* __restrict__ b_score,
    const int* __restrict__ ih, const int* __restrict__ iw,
    float* __restrict__ out_locs, float* __restrict__ out_scores,
    float* __restrict__ boxes, unsigned* __restrict__ keys,
    unsigned* __restrict__ hist, float* __restrict__ out_anchor) {
#pragma clang fp contract(off)
  const int y  = blockIdx.x, n = blockIdx.y, hf = blockIdx.z;
  const int t = threadIdx.x;
  const int lane = t & 63;
  const int pg = t >> 4;
  const int cg = t & 15;
  __shared__ float fl2[128 * 34];
  __shared__ float wl2[128 * 64];
  float acc[2][4];
#pragma unroll
  for (int i = 0; i < 2; ++i)
#pragma unroll
    for (int j = 0; j < 4; ++j) acc[i][j] = 0.f;

  const float* fb = feat2 + ((size_t)n * NPIX + y * 64 + hf * 32) * 512;
  for (int ch = 0; ch < 512; ch += 128) {
    for (int idx = t; idx < 32 * 128; idx += 256) {
      int p = idx >> 7, ic = idx & 127;
      fl2[ic * 34 + p] = fb[(size_t)p * 512 + ch + ic];
    }
    for (int idx = t; idx < 64 * 128; idx += 256) {
      int c = idx & 63, ic = idx >> 6;
      float v = 0.f;
      if (c < 36) v = w_loc[c * 512 + ch + ic];
      else if (c < 54) v = w_score[(c - 36) * 512 + ch + ic];
      wl2[ic * 64 + c] = v;
    }
    __syncthreads();
#pragma unroll 4
    for (int ic = 0; ic < 128; ++ic) {
      float2 f = *(const float2*)&fl2[ic * 34 + pg * 2];
      float4 w = *(const float4*)&wl2[ic * 64 + cg * 4];
      float fv[2] = {f.x, f.y};
      float wv[4] = {w.x, w.y, w.z, w.w};
#pragma unroll
      for (int i = 0; i < 2; ++i)
#pragma unroll
        for (int j = 0; j < 4; ++j)
          acc[i][j] = fmaf(wv[j], fv[i], acc[i][j]);
    }
    __syncthreads();
  }
#pragma unroll
  for (int j = 0; j < 4; ++j) {
    int c = cg * 4 + j;
    float bias = (c < 36) ? b_loc[c] : (c < 54 ? b_score[c - 36] : 0.f);
#pragma unroll
    for (int i = 0; i < 2; ++i) {
      int pxl = pg * 2 + i;
      float v = acc[i][j] + bias;
      size_t pix0 = (size_t)y * 64 + hf * 32 + pxl;
      if (c < 36) {
        out_locs[((size_t)n * NPIX + pix0) * 36 + c] = v;
        fl2[pxl * 56 + c] = v;
      } else if (c < 54) {
        out_scores[((size_t)n * NPIX + pix0) * 18 + (c - 36)] = v;
        fl2[pxl * 56 + c] = v;
      }
    }
  }
  __syncthreads();
  for (int task = t; task < 288; task += 256) {
    int lpx = task / 9;
    int a   = task - lpx * 9;
    int xq = hf * 32 + lpx, yq = y;
    int i = (yq * 64 + xq) * 9 + a;
    int gid = n * NANCH + i;
    int ri = a / 3, si = a - ri * 3;
    double ratio = (ri == 0) ? 0.5 : (ri == 1 ? 1.0 : 2.0);
    double scl   = (si == 0) ? 8.0 : (si == 1 ? 16.0 : 32.0);
    double hh = 16.0 * scl * sqrt(ratio);
    double ww = 16.0 * scl * sqrt(1.0 / ratio);
    float sx = (float)(xq * 16), sy = (float)(yq * 16);
    float ax1 = (float)(8.0 - ww * 0.5) + sx;
    float ay1 = (float)(8.0 - hh * 0.5) + sy;
    float ax2 = (float)(8.0 + ww * 0.5) + sx;
    float ay2 = (float)(8.0 + hh * 0.5) + sy;
    if (n == 0) {
      *(float4*)(out_anchor + (size_t)i * 4) = make_float4(ax1, ay1, ax2, ay2);
    }
    float l0 = fl2[lpx * 56 + a * 4 + 0];
    float l1 = fl2[lpx * 56 + a * 4 + 1];
    float l2 = fl2[lpx * 56 + a * 4 + 2];
    float l3 = fl2[lpx * 56 + a * 4 + 3];
    float aw = ax2 - ax1, ah = ay2 - ay1;
    float cx = ax1 + 0.5f * aw, cy = ay1 + 0.5f * ah;
    float ctrx = l0 * aw + cx, ctry = l1 * ah + cy;
    float nw = expf(l2) * aw, nh = expf(l3) * ah;
    float x1 = ctrx - 0.5f * nw, y1 = ctry - 0.5f * nh;
    float x2 = ctrx + 0.5f * nw, y2 = ctry + 0.5f * nh;
    float W = (float)iw[0], H = (float)ih[0];
    x1 = fminf(fmaxf(x1, 0.f), W);
    y1 = fminf(fmaxf(y1, 0.f), H);
    x2 = fminf(fmaxf(x2, 0.f), W);
    y2 = fminf(fmaxf(y2, 0.f), H);
    bool valid = ((x2 - x1) >= 16.f) && ((y2 - y1) >= 16.f);
    float s0 = fl2[lpx * 56 + 36 + a * 2];
    float s1 = fl2[lpx * 56 + 36 + a * 2 + 1];
    float mx = fmaxf(s0, s1);
    float e0 = expf(s0 - mx), e1 = expf(s1 - mx);
    float fg = e1 / (e0 + e1);
    float sc = valid ? fg : -1e9f;
    unsigned bb = __float_as_uint(sc);
    unsigned v = (bb & 0x80000000u) ? ~bb : (bb | 0x80000000u);
    keys[gid] = v;
    *(float4*)(boxes + (size_t)gid * 4) = make_float4(x1, y1, x2, y2);
    unsigned bin = v >> 16;
    unsigned tix = ((bin & 255u) << 8) | (bin >> 8);
    unsigned long long mv = __ballot(!valid);
    if (!valid) {
      int leader = __ffsll(mv) - 1;
      if (lane == leader)
        atomicAdd(&hist[(size_t)n * 65536 + tix], (unsigned)__popcll(mv));
    } else {
      atomicAdd(&hist[(size_t)n * 65536 + tix], 1u);
    }
  }
}

__global__ __launch_bounds__(256) void compact_kernel(
    const unsigned* __restrict__ keys, const unsigned* __restrict__ hist,
    unsigned* __restrict__ cnt, unsigned long long* __restrict__ cand) {
  int t = threadIdx.x;
  int gid = blockIdx.x * 256 + t;
  int lane = t & 63;
  int n = (blockIdx.x << 8) / NANCH;
  int i = gid - n * NANCH;
  const unsigned* h = hist + (size_t)n * 65536;
  __shared__ unsigned csum[256];
  __shared__ unsigned fine[256];
  __shared__ unsigned csel, cumsh, cutsh;
  unsigned s = 0;
  for (int low = 0; low < 256; ++low) s += h[low * 256 + t];
  csum[t] = s;
  __syncthreads();
  if (t == 0) {
    unsigned cum = 0;
    int c = 255;
    for (; c > 0; --c) {
      if (cum + csum[c] >= PREN) break;
      cum += csum[c];
    }
    csel = (unsigned)c;
    cumsh = cum;
  }
  __syncthreads();
  int c = (int)csel;
  fine[t] = h[t * 256 + c];
  __syncthreads();
  if (t == 0) {
    unsigned cum = cumsh;
    unsigned P = (unsigned)(c << 8);
    for (int low = 255; low >= 0; --low) {
      cum += fine[low];
      if (cum >= PREN) { P = (unsigned)((c << 8) | low); break; }
    }
    cutsh = P;
  }
  __syncthreads();
  unsigned P = cutsh;
  unsigned v = keys[gid];
  bool take = (v >> 16) >= P;
  unsigned long long m = __ballot(take);
  if (take) {
    int leader = __ffsll(m) - 1;
    int tot = __popcll(m);
    int pre = __popcll(m & ((lane == 0) ? 0ull : (~0ull >> (64 - lane))));
    unsigned base = 0;
    if (lane == leader) base = atomicAdd(&cnt[n], (unsigned)tot);
    base = __shfl(base, leader);
    cand[(size_t)n * NANCH + base + pre] =
        ((unsigned long long)v << 32) | (unsigned)(~i);
  }
}

__global__ __launch_bounds__(256) void rank2_kernel(
    const unsigned long long* __restrict__ cand, const unsigned* __restrict__ cnt,
    const float* __restrict__ boxes, float* __restrict__ sboxes) {
  int n = blockIdx.y;
  int C = (int)cnt[n];
  if (blockIdx.x * 256 >= C) return;
  int t = threadIdx.x;
  int i = blockIdx.x * 256 + t;
  const unsigned long long* cb = cand + (size_t)n * NANCH;
  unsigned long long Ki = (i < C) ? cb[i] : 0ull;
  __shared__ unsigned long long tile[256];
  int rank = 0;
  for (int t0 = 0; t0 < C; t0 += 256) {
    __syncthreads();
    int j = t0 + t;
    tile[t] = (j < C) ? cb[j] : 0ull;
    __syncthreads();
#pragma unroll 16
    for (int jj = 0; jj < 256; ++jj)
      rank += (tile[jj] > Ki) ? 1 : 0;
  }
  if (i < C && rank < PREN) {
    unsigned orig = ~(unsigned)(Ki & 0xffffffffull);
    float4 bb = *(const float4*)(boxes + ((size_t)n * NANCH + orig) * 4);
    *(float4*)(sboxes + ((size_t)n * PREN + rank) * 4) = bb;
  }
}

__global__ __launch_bounds__(256) void iou_kernel(
    const float* __restrict__ sboxes, unsigned long long* __restrict__ sup) {
#pragma clang fp contract(off)
  int n = blockIdx.y, i = blockIdx.x;
  const float* B = sboxes + (size_t)n * PREN * 4;
  float4 bi = *(const float4*)(B + (size_t)i * 4);
  float area_i = (bi.z - bi.x) * (bi.w - bi.y);
  int lane = threadIdx.x & 63, wv = threadIdx.x >> 6;
  unsigned long long* row = sup + ((size_t)n * PREN + i) * 64;
  for (int w0 = wv; w0 < 64; w0 += 4) {
    int j = w0 * 64 + lane;
    bool p = false;
    if (j < PREN) {
      float4 bj = *(const float4*)(B + (size_t)j * 4);
      float area_j = (bj.z - bj.x) * (bj.w - bj.y);
      float x1 = fmaxf(bi.x, bj.x), y1 = fmaxf(bi.y, bj.y);
      float x2 = fminf(bi.z, bj.z), y2 = fminf(bi.w, bj.w);
      float inter = fmaxf(x2 - x1, 0.f) * fmaxf(y2 - y1, 0.f);
      float iou = inter / (area_i + area_j - inter + 1e-9f);
      p = iou > 0.7f;
    }
    unsigned long long m = __ballot(p);
    if (lane == 0) row[w0] = m;
  }
}

__global__ __launch_bounds__(64) void nms_kernel(
    const unsigned long long* __restrict__ sup, const float* __restrict__ sboxes,
    float* __restrict__ rois, float* __restrict__ ridx) {
  int n = blockIdx.x;
  int lane = threadIdx.x;
  const unsigned long long* S = sup + (size_t)n * PREN * 64;
  unsigned long long buf[64];
#pragma unroll
  for (int bq = 0; bq < 64; ++bq) buf[bq] = S[(size_t)bq * 64 + lane];
  unsigned long long keep = (lane < 46) ? ~0ull
                          : (lane == 46 ? ((1ull << 56) - 1ull) : 0ull);
  for (int w = 0; w < 47; ++w) {
    unsigned long long kw = __shfl(keep, w);
    unsigned long long gtmask = (lane > w) ? ~0ull : 0ull;
#pragma unroll
    for (int bq = 0; bq < 64; ++bq) {
      const int i = w * 64 + bq;
      unsigned long long r = buf[bq];
      if (i + 64 < PREN) buf[bq] = S[(size_t)(i + 64) * 64 + lane];
      unsigned long long rw = __shfl(r, w);
      unsigned long long amask = ((kw >> bq) & 1ull) ? ~0ull : 0ull;
      const unsigned long long fmask = (bq == 63) ? 0ull : ~((2ull << bq) - 1ull);
      kw &= ~(rw & fmask & amask);
      keep &= ~(r & gtmask & amask);
    }
    keep = (lane == w) ? kw : keep;
  }
  int cnt = __popcll(keep);
  int scn = cnt;
  for (int d = 1; d < 64; d <<= 1) {
    int v = __shfl_up(scn, d);
    if (lane >= d) scn += v;
  }
  int excl = scn - cnt;
  int total = __shfl(scn, 63);
  const float* SB = sboxes + (size_t)n * PREN * 4;
  unsigned long long kk = keep;
  int p = excl;
  while (kk) {
    int bpos = __ffsll(kk) - 1;
    kk &= kk - 1ull;
    if (p < POSTN) {
      float4 bb = *(const float4*)(SB + (size_t)(lane * 64 + bpos) * 4);
      *(float4*)(rois + ((size_t)n * POSTN + p) * 4) = bb;
    }
    ++p;
  }
  if (lane == 0) {
    float4 b0 = *(const float4*)SB;
    for (int q = total; q < POSTN; ++q)
      *(float4*)(rois + ((size_t)n * POSTN + q) * 4) = b0;
  }
  for (int q = lane; q < POSTN; q += 64) ridx[n * POSTN + q] = (float)n;
}

extern "C" void kernel_launch(void* const* d_in, const int* in_sizes, int n_in,
                              void* d_out, int out_size, void* d_ws, size_t ws_size,
                              hipStream_t stream) {
  const float* x       = (const float*)d_in[0];
  const float* w_conv  = (const float*)d_in[1];
  const float* b_conv  = (const float*)d_in[2];
  const float* w_score = (const float*)d_in[3];
  const float* b_score = (const float*)d_in[4];
  const float* w_loc   = (const float*)d_in[5];
  const float* b_loc   = (const float*)d_in[6];
  const int*   img_h   = (const int*)d_in[7];
  const int*   img_w   = (const int*)d_in[8];

  float* out        = (float*)d_out;
  float* out_locs   = out;
  float* out_scores = out + 589824;
  float* out_rois   = out + 884736;
  float* out_ridx   = out + 889536;
  float* out_anchor = out + 890736;

  const size_t NEED = 76546112;   // feat2 33.55M | wt 9.44M | xt 33.55M | zpage 64B
  if (ws_size >= NEED) {
    // ---- MFMA path (f16x2 split, B->reg, A dbuf, 1 barrier/icc) ----
    float* feat2 = (float*)d_ws;                                   // 33,554,432 B
    short* wth   = (short*)((char*)d_ws + 33554432);               //  4,718,592 B
    short* wtl   = wth + 2359296;                                  //  4,718,592 B
    short* xth   = (short*)((char*)d_ws + 42991616);               // 16,777,216 B
    short* xtl   = xth + 8388608;                                  // 16,777,216 B
    char*  zpage = (char*)d_ws + 76546048;                         //         64 B
    // post-conv aliases: boxes region over wt (dead), hist/cand over xt (dead)
    float* boxes = (float*)wth;                                    // 2,359,296 B
    unsigned* keys = (unsigned*)(boxes + 589824);
    float* sboxes  = (float*)(keys + 147456);
    unsigned long long* sup = (unsigned long long*)(sboxes + 48000);
    unsigned* hist = (unsigned*)xth;
    unsigned* cnt  = hist + 262148;
    unsigned long long* cand = (unsigned long long*)(hist + 262160);

    xform_w_kernel<<<512, 256, 0, stream>>>(w_conv, wth, wtl, (unsigned*)zpage);
    xform_x_kernel<<<dim3(64, 4), 256, 0, stream>>>(x, xth, xtl);
    conv3_mfma<<<dim3(32, 4, 4), 256, 0, stream>>>(xth, xtl, wth, wtl, b_conv,
                                                   zpage, feat2);
    zero_hist_kernel<<<1025, 256, 0, stream>>>(hist);
    conv1_decode_kernel<<<dim3(64, 4, 2), 256, 0, stream>>>(
        feat2, w_loc, b_loc, w_score, b_score, img_h, img_w,
        out_locs, out_scores, boxes, keys, hist, out_anchor);
    compact_kernel<<<576, 256, 0, stream>>>(keys, hist, cnt, cand);
    rank2_kernel<<<dim3(144, 4), 256, 0, stream>>>(cand, cnt, boxes, sboxes);
    iou_kernel<<<dim3(PREN, 4), 256, 0, stream>>>(sboxes, sup);
    nms_kernel<<<4, 64, 0, stream>>>(sup, sboxes, out_rois, out_ridx);
  } else {
    // ---- fallback: previous fp32 pipeline (ws too small for MFMA path) ----
    float* feat2 = (float*)d_ws;
    float* A     = feat2 + (size_t)8388608;
    float* w4    = A;
    float* boxes = A;
    unsigned* keys = (unsigned*)(boxes + 589824);
    float* sboxes  = (float*)(keys + 147456);
    unsigned long long* sup = (unsigned long long*)(sboxes + 48000);
    unsigned* hist = (unsigned*)(A + 2359296);
    unsigned* cnt  = hist + 262148;
    unsigned long long* cand = (unsigned long long*)(hist + 262160);

    reshape_w_kernel<<<9216, 256, 0, stream>>>(w_conv, w4, hist);
    conv3_kernel<<<dim3(16, 16, 4), 256, 0, stream>>>(x, w4, b_conv, feat2);
    conv1_decode_kernel<<<dim3(64, 4, 2), 256, 0, stream>>>(
        feat2, w_loc, b_loc, w_score, b_score, img_h, img_w,
        out_locs, out_scores, boxes, keys, hist, out_anchor);
    compact_kernel<<<576, 256, 0, stream>>>(keys, hist, cnt, cand);
    rank2_kernel<<<dim3(144, 4), 256, 0, stream>>>(cand, cnt, boxes, sboxes);
    iou_kernel<<<dim3(PREN, 4), 256, 0, stream>>>(sboxes, sup);
    nms_kernel<<<4, 64, 0, stream>>>(sup, sboxes, out_rois, out_ridx);
  }
}

// Round 10
// 750.468 us; speedup vs baseline: 1.5365x; 1.2999x over previous
//
#include <hip/hip_runtime.h>
#include <cstdint>
#include <cmath>

#define HW 64
#define NPIX 4096          // 64*64
#define CIN 512
#define NANCH 36864        // 4096*9
#define PREN 3000
#define POSTN 300
#define ICL 8
#define NSLOT 13           // ceil(8*6*66 / 256), last slot: 96 threads

typedef _Float16 h8v __attribute__((ext_vector_type(8)));
typedef float f16v __attribute__((ext_vector_type(16)));

#define AS1 __attribute__((address_space(1)))
#define AS3 __attribute__((address_space(3)))

__device__ __forceinline__ void gl16(const void* g, void* l) {
  __builtin_amdgcn_global_load_lds((const AS1 void*)g, (AS3 void*)l, 16, 0, 0);
}

// f16 two-term split: f = h + l with |f-h-l| <= |f|*2^-22 (f pre-scaled so
// both h and l stay in f16 normal range; scaling by 2^k is exact).
__device__ __forceinline__ void f16_split(float f, short& h, short& l) {
  _Float16 hh = (_Float16)f;
  float hf = (float)hh;
  _Float16 ll = (_Float16)(f - hf);
  h = __builtin_bit_cast(short, hh);
  l = __builtin_bit_cast(short, ll);
}

// ==================== MFMA PATH: f16x2-split conv ====================

// ---- w (512oc,512ic,3,3) fp32 -> wth/wtl fragment-major f16 hi/lo, x128 ----
// Layout (shorts): [tap][icc][kh][lh][oc 0..511][8 ic]
__global__ __launch_bounds__(256) void xform_w_kernel(
    const float* __restrict__ w, short* __restrict__ wth,
    short* __restrict__ wtl, unsigned* __restrict__ zp) {
  const int oc = blockIdx.x;
  const int t = threadIdx.x;
  __shared__ float ws_[4608];
  const float* wr = w + (size_t)oc * 4608;
  for (int i = t; i < 4608; i += 256) ws_[i] = wr[i];
  __syncthreads();
  for (int c = t; c < 576; c += 256) {
    int tap = c / 64;
    int g = c - tap * 64;            // ic-group of 8: ic = g*8 .. g*8+7
    int icc = g >> 2;
    int kh = (g >> 1) & 1;
    int lhh = g & 1;
    h8v hv, lv;
    short* hp = (short*)&hv;
    short* lp = (short*)&lv;
#pragma unroll
    for (int j = 0; j < 8; ++j) {
      short hh, ll;
      f16_split(ws_[(g * 8 + j) * 9 + tap] * 128.0f, hh, ll);
      hp[j] = hh; lp[j] = ll;
    }
    long o = (((((long)tap * 16 + icc) * 2 + kh) * 2 + lhh) * 512 + oc) * 8;
    *(h8v*)(wth + o) = hv;
    *(h8v*)(wtl + o) = lv;
  }
  if (oc == 0 && t < 16) zp[t] = 0u;   // zero-page for halo redirect
}

// ---- x NCHW fp32 -> xth/xtl [n][y][x][ic] f16 hi/lo (NHWC), x2048 ----
__global__ __launch_bounds__(256) void xform_x_kernel(
    const float* __restrict__ x, short* __restrict__ xth,
    short* __restrict__ xtl) {
  const int yb = blockIdx.x;   // 0..63
  const int n = blockIdx.y;
  const int t = threadIdx.x;
  __shared__ float xs[64 * 65];
  const float* xr = x + ((size_t)n * 512) * 4096 + yb * 64;
  short* oh = xth + ((size_t)n * 4096 + yb * 64) * 512;
  short* ol = xtl + ((size_t)n * 4096 + yb * 64) * 512;
  for (int icb = 0; icb < 8; ++icb) {
    if (icb) __syncthreads();
#pragma unroll
    for (int q = 0; q < 16; ++q) {
      int idx = q * 256 + t;
      int icl = idx >> 6, xc = idx & 63;
      xs[icl * 65 + xc] = xr[(size_t)(icb * 64 + icl) * 4096 + xc];
    }
    __syncthreads();
#pragma unroll
    for (int q = 0; q < 2; ++q) {
      int c = q * 256 + t;
      int xc = c >> 3, icg = c & 7;
      h8v hv, lv;
      short* hp = (short*)&hv;
      short* lp = (short*)&lv;
#pragma unroll
      for (int j = 0; j < 8; ++j) {
        short hh, ll;
        f16_split(xs[(icg * 8 + j) * 65 + xc] * 2048.0f, hh, ll);
        hp[j] = hh; lp[j] = ll;
      }
      size_t o = (size_t)xc * 512 + icb * 64 + icg * 8;
      *(h8v*)(oh + o) = hv;
      *(h8v*)(ol + o) = lv;
    }
  }
}

// ---- 3x3 conv via implicit GEMM on matrix cores, f16x2 split (3 MFMA) ----
// grid (32 ypair-raw, 4, 4n), 256 thr = 4 waves; block tile 2rows x 64cols x 128oc.
// A-slab: LDS DOUBLE-buffered (69632 B). B: global->VGPR (L2-resident),
// prefetched 1 tap ahead via single Bcur/Bnxt pair.
// R10: R7's proven ROLLED 144-step loop (112 VGPR, no spill — R8/R9's
// unrolled tap loop let the scheduler hoist 9 B-load generations -> spill,
// WRITE_SIZE 32->220+ MB). Only change vs R7: next-icc A restage issued at
// TAP 0 into buf^1, ONE barrier per icc (gl16s 9 taps old -> drain ~free;
// R7's 2nd barrier drained freshly-issued gl16s = L2 latency x16).
// Result scaled 2^18; chunked S-drain per icc (bit-identical to R3 order).
__global__ __launch_bounds__(256, 2) void conv3_mfma(
    const short* __restrict__ xth, const short* __restrict__ xtl,
    const short* __restrict__ wth, const short* __restrict__ wtl,
    const float* __restrict__ bconv, const char* __restrict__ zpage,
    float* __restrict__ feat2) {
  const int t = threadIdx.x;
  const int lane = t & 63;
  const int wid = __builtin_amdgcn_readfirstlane(t >> 6);
  const int l31 = lane & 31, lh = lane >> 5;
  const int wm = wid >> 1, wn = wid & 1;

  // XCD-aware swizzle: each XCD (bx%8) owns one 128-oc weight panel (L2-fit).
  const int bx = blockIdx.x, by = blockIdx.y, n = blockIdx.z;
  const int k8 = bx & 7;
  const int ocb = k8 & 3;
  const int yp = (k8 >> 2) * 16 + (bx >> 3) * 4 + by;  // 0..31
  const int y0 = yp * 2;
  const int ocbase = ocb * 128;

  __shared__ short As[2][2][272 * 32];   // [abuf][hilo][...] 69632 B
  char* const asb = (char*)&As[0][0][0];

  // ---- A staging descriptors: 34x 1KB blocks over 4 waves ----
  const char* asrc[9]; int adst[9]; int astep[9];
  {
    const char* xs0 = (const char*)xth;
    const char* xs1 = (const char*)xtl;
#pragma unroll
    for (int k = 0; k < 9; ++k) {
      int bq = wid + 4 * k;
      if (bq < 34) {
        int hl = (bq >= 17) ? 1 : 0;
        int blk = bq - hl * 17;
        int e = blk * 16 + (lane >> 2);
        int slot = lane & 3;
        int r = e / 68;
        int cp = e - r * 68;
        int y = y0 - 1 + r;
        int c = cp - 1;
        bool valid = (cp >= 1) && (cp <= 64) && (y >= 0) && (y < 64);
        int ss = slot ^ ((e >> 1) & 3);                 // source pre-swizzle
        long off = ((((long)n * 64 + y) * 64 + c) * 512 + ss * 8) * 2;
        asrc[k] = valid ? ((hl ? xs1 : xs0) + off) : (const char*)zpage;
        astep[k] = valid ? 64 : 0;                      // 32 ic * 2B per icc
        adst[k] = hl * 17408 + blk * 1024;
      }
    }
  }

  // ---- B fragment global base: lane-constant offset (shorts) ----
  const long lane_b = (long)lh * 4096 + (long)(ocbase + wn * 64 + l31) * 8;

  struct FragB { h8v h[2][2], l[2][2]; };   // [kh][fn]

#define READ_Bg(F, TAP, ICC) do {                                            \
    long sb_ = ((long)(TAP) * 16 + (ICC)) * 16384 + lane_b;                  \
    _Pragma("unroll")                                                        \
    for (int kh_ = 0; kh_ < 2; ++kh_)                                        \
      _Pragma("unroll")                                                      \
      for (int fn_ = 0; fn_ < 2; ++fn_) {                                    \
        long o_ = sb_ + kh_ * 8192 + fn_ * 256;                              \
        (F).h[kh_][fn_] = *(const h8v*)(wth + o_);                           \
        (F).l[kh_][fn_] = *(const h8v*)(wtl + o_);                           \
      }                                                                      \
  } while (0)

#define COMP_AE(AE, TAP) do {                                                 \
    int dy_ = (TAP) / 3, dx_ = (TAP) - dy_ * 3;                               \
    _Pragma("unroll")                                                         \
    for (int fm_ = 0; fm_ < 2; ++fm_) {                                       \
      int e_ = (wm + dy_) * 68 + fm_ * 32 + l31 + dx_;                        \
      (AE)[fm_] = e_ * 64 + ((lh ^ ((e_ >> 1) & 3)) << 4);                    \
    }                                                                         \
  } while (0)

  // per kh: read 4 A granules from LDS (inline), then 12 MFMAs (R3 order).
#define TAP_MFMA(BC, AB) do {                                                 \
    _Pragma("unroll")                                                         \
    for (int kh_ = 0; kh_ < 2; ++kh_) {                                       \
      h8v Ah_[2], Al_[2];                                                     \
      _Pragma("unroll")                                                       \
      for (int fm_ = 0; fm_ < 2; ++fm_) {                                     \
        int a0_ = ae[fm_] ^ (kh_ << 5);                                       \
        Ah_[fm_] = *(const h8v*)((AB) + a0_);                                 \
        Al_[fm_] = *(const h8v*)((AB) + 17408 + a0_);                         \
      }                                                                       \
      _Pragma("unroll")                                                       \
      for (int fm_ = 0; fm_ < 2; ++fm_)                                       \
        _Pragma("unroll")                                                     \
        for (int fn_ = 0; fn_ < 2; ++fn_)                                     \
          acc[fm_][fn_] = __builtin_amdgcn_mfma_f32_32x32x16_f16(             \
              Ah_[fm_], (BC).h[kh_][fn_], acc[fm_][fn_], 0, 0, 0);            \
      _Pragma("unroll")                                                       \
      for (int fm_ = 0; fm_ < 2; ++fm_)                                       \
        _Pragma("unroll")                                                     \
        for (int fn_ = 0; fn_ < 2; ++fn_)                                     \
          acc[fm_][fn_] = __builtin_amdgcn_mfma_f32_32x32x16_f16(             \
              Al_[fm_], (BC).h[kh_][fn_], acc[fm_][fn_], 0, 0, 0);            \
      _Pragma("unroll")                                                       \
      for (int fm_ = 0; fm_ < 2; ++fm_)                                       \
        _Pragma("unroll")                                                     \
        for (int fn_ = 0; fn_ < 2; ++fn_)                                     \
          acc[fm_][fn_] = __builtin_amdgcn_mfma_f32_32x32x16_f16(             \
              Ah_[fm_], (BC).l[kh_][fn_], acc[fm_][fn_], 0, 0, 0);            \
    }                                                                         \
  } while (0)

  // Rolled step body (R7 shape). A restage at tap 0 -> buf^1; one barrier.
#define STEP_BODY(BC, BN) do {                                                \
    int tapN_ = tap + 1, iccN_ = icc;                                         \
    if (tapN_ == 9) { tapN_ = 0; iccN_ = (icc < 15) ? icc + 1 : 15; }         \
    READ_Bg(BN, tapN_, iccN_);            /* per-wave B prefetch (1 ahead) */ \
    if (tap == 0 && icc < 15) {           /* stage NEXT icc A -> other buf */ \
      char* ab_ = asb + ((acur ^ 1) * 34816);                                 \
      _Pragma("unroll")                                                       \
      for (int k_ = 0; k_ < 9; ++k_) {                                        \
        int bq_ = wid + 4 * k_;                                               \
        if (bq_ < 34) { asrc[k_] += astep[k_];                                \
                        gl16(asrc[k_], ab_ + adst[k_]); }                     \
      }                                                                       \
    }                                                                         \
    COMP_AE(ae, tap);                                                         \
    { char* abc_ = asb + (acur * 34816);                                      \
      TAP_MFMA(BC, abc_); }                                                   \
    ++tap;                                                                    \
    if (tap == 9) {                       /* icc boundary */                  \
      tap = 0; ++icc;                                                         \
      _Pragma("unroll")                                                       \
      for (int fm_ = 0; fm_ < 2; ++fm_)                                       \
        _Pragma("unroll")                                                     \
        for (int fn_ = 0; fn_ < 2; ++fn_)                                     \
          _Pragma("unroll")                                                   \
          for (int r_ = 0; r_ < 16; ++r_) {                                   \
            S[fm_][fn_][r_] += acc[fm_][fn_][r_];                             \
            acc[fm_][fn_][r_] = 0.f;                                          \
          }                                                                   \
      __syncthreads();                    /* reads done; gl16s 9 taps old */  \
      acur ^= 1;                                                              \
    }                                                                         \
  } while (0)

  f16v acc[2][2];   // per-icc chunk accumulator (MFMA C)
  f16v S[2][2];     // running sum across chunks
#pragma unroll
  for (int i = 0; i < 2; ++i)
#pragma unroll
    for (int j = 0; j < 2; ++j)
#pragma unroll
      for (int r = 0; r < 16; ++r) { acc[i][j][r] = 0.f; S[i][j][r] = 0.f; }

  // prologue: A(icc=0) -> buf0; B(0,0) -> regs
#pragma unroll
  for (int k = 0; k < 9; ++k) {
    int bq = wid + 4 * k;
    if (bq < 34) gl16(asrc[k], asb + adst[k]);
  }
  FragB B0, B1;
  READ_Bg(B0, 0, 0);
  __syncthreads();
  int ae[2];
  int tap = 0, icc = 0, acur = 0;

  for (int s2 = 0; s2 < 72; ++s2) {       // 144 steps, rolled ping-pong
    STEP_BODY(B0, B1);
    STEP_BODY(B1, B0);
  }

#undef READ_Bg
#undef COMP_AE
#undef TAP_MFMA
#undef STEP_BODY

  // ---- epilogue: unscale + bias + ReLU -> feat2 NHWC ----
  const float OS = 1.0f / 262144.0f;       // 2^-18 (x*2^11 * w*2^7)
  const float* bb = bconv + ocbase + wn * 64;
#pragma unroll
  for (int fn = 0; fn < 2; ++fn) {
    const float bias = bb[fn * 32 + l31];
#pragma unroll
    for (int fm = 0; fm < 2; ++fm) {
      float* op = feat2 + (((long)n * 4096 + (y0 + wm) * 64 + fm * 32) * 512)
                + ocbase + wn * 64 + fn * 32 + l31;
#pragma unroll
      for (int r = 0; r < 16; ++r) {
        int m = (r & 3) + 8 * (r >> 2) + 4 * lh;
        op[(long)m * 512] = fmaxf(S[fm][fn][r] * OS + bias, 0.f);
      }
    }
  }
}

__global__ __launch_bounds__(256) void zero_hist_kernel(unsigned* __restrict__ h) {
  int i = blockIdx.x * 256 + threadIdx.x;
  if (i < 262160) h[i] = 0u;
}

// ============== OLD PATH (fallback if ws_size is too small) ==============
__global__ __launch_bounds__(256) void reshape_w_kernel(
    const float* __restrict__ w, float* __restrict__ w4,
    unsigned* __restrict__ histz) {
  int gid = blockIdx.x * 256 + threadIdx.x;
  if (gid < 262160) histz[gid] = 0;
  if (gid >= 512 * 512 * 9) return;
  int o4  = gid & 3;
  int r   = gid >> 2;
  int tap = r % 9;
  int r2  = r / 9;
  int h   = r2 & 1;
  int r3  = r2 >> 1;
  int ic  = r3 & 511;
  int g   = r3 >> 9;
  int oc  = (g >> 2) * 32 + (g & 3) * 8 + h * 4 + o4;
  w4[gid] = w[((size_t)oc * 512 + ic) * 9 + tap];
}

#define WLOAD(DST, UPTR) do {                                                \
    _Pragma("unroll")                                                        \
    for (int q = 0; q < 36; ++q) (DST)[q] = (UPTR)[q];                       \
  } while (0)

#define CONV_HALF(W, OB) do {                                                \
    _Pragma("unroll")                                                        \
    for (int r = 0; r < 3; ++r)                                              \
    _Pragma("unroll")                                                        \
    for (int kx = 0; kx < 3; ++kx) {                                         \
      _Pragma("unroll")                                                      \
      for (int o = 0; o < 4; ++o) {                                          \
        const float wv = (W)[(r * 3 + kx) * 4 + o];                          \
        _Pragma("unroll")                                                    \
        for (int j = 0; j < 4; ++j)                                          \
          acc[(OB) + o][j] = fmaf(wv, xr[r][j + kx], acc[(OB) + o][j]);      \
      }                                                                      \
    }                                                                        \
  } while (0)

__global__ __launch_bounds__(256, 4) void conv3_kernel(
    const float* __restrict__ x, const float* __restrict__ w4,
    const float* __restrict__ b, float* __restrict__ feat2) {
  const int oct = blockIdx.x;
  const int yt  = blockIdx.y;
  const int n   = blockIdx.z;
  const int t   = threadIdx.x;
  const int wid  = __builtin_amdgcn_readfirstlane(t >> 6);
  const int lane = t & 63;
  const int lrow = lane >> 4;
  const int lcol = (lane & 15) << 2;
  const int y0 = yt << 2;

  __shared__ float xs[2][ICL * 6 * 68];

  float acc[8][4];
#pragma unroll
  for (int o = 0; o < 8; ++o)
#pragma unroll
    for (int j = 0; j < 4; ++j) acc[o][j] = 0.f;

  const float* xb = x + (size_t)n * CIN * NPIX;
  const float* __restrict__ wq = w4 + (size_t)(oct * 4 + wid) * (512 * 72);

  int  goff[NSLOT];
  int  laddr[NSLOT];
  bool val[NSLOT];
#pragma unroll
  for (int k = 0; k < NSLOT; ++k) {
    int s   = t + (k << 8);
    int icl = s / 396;
    int rem = s - icl * 396;
    int row = rem / 66;
    int c   = rem - row * 66;
    int yy = y0 - 1 + row;
    int xx = c - 1;
    bool act = (k < NSLOT - 1) || (t < 96);
    val[k]  = act && ((unsigned)yy < 64u) && ((unsigned)xx < 64u);
    goff[k] = icl * NPIX + yy * 64 + xx;
    laddr[k] = icl * 408 + row * 68 + c;
  }

  {
    float v[NSLOT];
#pragma unroll
    for (int k = 0; k < NSLOT; ++k) v[k] = val[k] ? xb[goff[k]] : 0.f;
#pragma unroll
    for (int k = 0; k < NSLOT; ++k)
      if (k < NSLOT - 1 || t < 96) xs[0][laddr[k]] = v[k];
  }

  float wbA[36], wbB[36];
  WLOAD(wbA, wq);

  for (int cch = 0; cch < 64; ++cch) {
    const int cur = cch & 1;
    float rn[NSLOT];
    if (cch < 63) {
      const float* xn = xb + (size_t)(cch + 1) * (ICL * NPIX);
#pragma unroll
      for (int k = 0; k < NSLOT; ++k) rn[k] = val[k] ? xn[goff[k]] : 0.f;
    }
    __syncthreads();
#pragma unroll 1
    for (int icl = 0; icl < ICL; ++icl) {
      const int u0 = (cch << 4) + (icl << 1);
      const float* xp = &xs[cur][icl * 408 + lrow * 68 + lcol];
      float4 a0 = *(const float4*)(xp);
      float2 b0 = *(const float2*)(xp + 4);
      float4 a1 = *(const float4*)(xp + 68);
      float2 b1 = *(const float2*)(xp + 72);
      float4 a2 = *(const float4*)(xp + 136);
      float2 b2 = *(const float2*)(xp + 140);
      float xr[3][6] = {{a0.x, a0.y, a0.z, a0.w, b0.x, b0.y},
                        {a1.x, a1.y, a1.z, a1.w, b1.x, b1.y},
                        {a2.x, a2.y, a2.z, a2.w, b2.x, b2.y}};
      WLOAD(wbB, wq + (size_t)(u0 + 1) * 36);
      CONV_HALF(wbA, 0);
      {
        const int un = (u0 + 2 < 1024) ? (u0 + 2) : 1023;
        WLOAD(wbA, wq + (size_t)un * 36);
      }
      CONV_HALF(wbB, 4);
    }
    if (cch < 63) {
#pragma unroll
      for (int k = 0; k < NSLOT; ++k)
        if (k < NSLOT - 1 || t < 96) xs[cur ^ 1][laddr[k]] = rn[k];
    }
  }

  const float* __restrict__ bs = b + oct * 32 + wid * 8;
  float bias[8];
#pragma unroll
  for (int o = 0; o < 8; ++o) bias[o] = bs[o];
  float* ob = feat2 + ((size_t)n * NPIX + (y0 + lrow) * 64 + lcol) * 512 + oct * 32 + wid * 8;
#pragma unroll
  for (int j = 0; j < 4; ++j) {
    float4 v0, v1;
    v0.x = fmaxf(acc[0][j] + bias[0], 0.f);
    v0.y = fmaxf(acc[1][j] + bias[1], 0.f);
    v0.z = fmaxf(acc[2][j] + bias[2], 0.f);
    v0.w = fmaxf(acc[3][j] + bias[3], 0.f);
    v1.x = fmaxf(acc[4][j] + bias[4], 0.f);
    v1.y = fmaxf(acc[5][j] + bias[5], 0.f);
    v1.z = fmaxf(acc[6][j] + bias[6], 0.f);
    v1.w = fmaxf(acc[7][j] + bias[7], 0.f);
    *(float4*)(ob + (size_t)j * 512)     = v0;
    *(float4*)(ob + (size_t)j * 512 + 4) = v1;
  }
}

// ================= shared tail kernels (unchanged) =================
__global__ __launch_bounds__(256) void conv1_decode_kernel(
    const float* __restrict__ feat2,
    const float* __restrict__ w_loc, const float* __restrict__ b_loc,
    const float* __restrict__ w_score, const float* __restrict__ b_score,
    const int* __restrict__ ih, const int* __restrict__ iw,
    float* __restrict__ out_locs, float* __restrict__ out_scores,
    float* __restrict__ boxes, unsigned* __restrict__ keys,
    unsigned* __restrict__ hist, float* __restrict__ out_anchor) {
#pragma clang fp contract(off)
  const int y  = blockIdx.x, n = blockIdx.y, hf = blockIdx.z;
  const int t = threadIdx.x;
  const int lane = t & 63;
  const int pg = t >> 4;
  const int cg = t & 15;
  __shared__ float fl2[128 * 34];
  __shared__ float wl2[128 * 64];
  float acc[2][4];
#pragma unroll
  for (int i = 0; i < 2; ++i)
#pragma unroll
    for (int j = 0; j < 4; ++j) acc[i][j] = 0.f;

  const float* fb = feat2 + ((size_t)n * NPIX + y * 64 + hf * 32) * 512;
  for (int ch = 0; ch < 512; ch += 128) {
    for (int idx = t; idx < 32 * 128; idx += 256) {
      int p = idx >> 7, ic = idx & 127;
      fl2[ic * 34 + p] = fb[(size_t)p * 512 + ch + ic];
    }
    for (int idx = t; idx < 64 * 128; idx += 256) {
      int c = idx & 63, ic = idx >> 6;
      float v = 0.f;
      if (c < 36) v = w_loc[c * 512 + ch + ic];
      else if (c < 54) v = w_score[(c - 36) * 512 + ch + ic];
      wl2[ic * 64 + c] = v;
    }
    __syncthreads();
#pragma unroll 4
    for (int ic = 0; ic < 128; ++ic) {
      float2 f = *(const float2*)&fl2[ic * 34 + pg * 2];
      float4 w = *(const float4*)&wl2[ic * 64 + cg * 4];
      float fv[2] = {f.x, f.y};
      float wv[4] = {w.x, w.y, w.z, w.w};
#pragma unroll
      for (int i = 0; i < 2; ++i)
#pragma unroll
        for (int j = 0; j < 4; ++j)
          acc[i][j] = fmaf(wv[j], fv[i], acc[i][j]);
    }
    __syncthreads();
  }
#pragma unroll
  for (int j = 0; j < 4; ++j) {
    int c = cg * 4 + j;
    float bias = (c < 36) ? b_loc[c] : (c < 54 ? b_score[c - 36] : 0.f);
#pragma unroll
    for (int i = 0; i < 2; ++i) {
      int pxl = pg * 2 + i;
      float v = acc[i][j] + bias;
      size_t pix0 = (size_t)y * 64 + hf * 32 + pxl;
      if (c < 36) {
        out_locs[((size_t)n * NPIX + pix0) * 36 + c] = v;
        fl2[pxl * 56 + c] = v;
      } else if (c < 54) {
        out_scores[((size_t)n * NPIX + pix0) * 18 + (c - 36)] = v;
        fl2[pxl * 56 + c] = v;
      }
    }
  }
  __syncthreads();
  for (int task = t; task < 288; task += 256) {
    int lpx = task / 9;
    int a   = task - lpx * 9;
    int xq = hf * 32 + lpx, yq = y;
    int i = (yq * 64 + xq) * 9 + a;
    int gid = n * NANCH + i;
    int ri = a / 3, si = a - ri * 3;
    double ratio = (ri == 0) ? 0.5 : (ri == 1 ? 1.0 : 2.0);
    double scl   = (si == 0) ? 8.0 : (si == 1 ? 16.0 : 32.0);
    double hh = 16.0 * scl * sqrt(ratio);
    double ww = 16.0 * scl * sqrt(1.0 / ratio);
    float sx = (float)(xq * 16), sy = (float)(yq * 16);
    float ax1 = (float)(8.0 - ww * 0.5) + sx;
    float ay1 = (float)(8.0 - hh * 0.5) + sy;
    float ax2 = (float)(8.0 + ww * 0.5) + sx;
    float ay2 = (float)(8.0 + hh * 0.5) + sy;
    if (n == 0) {
      *(float4*)(out_anchor + (size_t)i * 4) = make_float4(ax1, ay1, ax2, ay2);
    }
    float l0 = fl2[lpx * 56 + a * 4 + 0];
    float l1 = fl2[lpx * 56 + a * 4 + 1];
    float l2 = fl2[lpx * 56 + a * 4 + 2];
    float l3 = fl2[lpx * 56 + a * 4 + 3];
    float aw = ax2 - ax1, ah = ay2 - ay1;
    float cx = ax1 + 0.5f * aw, cy = ay1 + 0.5f * ah;
    float ctrx = l0 * aw + cx, ctry = l1 * ah + cy;
    float nw = expf(l2) * aw, nh = expf(l3) * ah;
    float x1 = ctrx - 0.5f * nw, y1 = ctry - 0.5f * nh;
    float x2 = ctrx + 0.5f * nw, y2 = ctry + 0.5f * nh;
    float W = (float)iw[0], H = (float)ih[0];
    x1 = fminf(fmaxf(x1, 0.f), W);
    y1 = fminf(fmaxf(y1, 0.f), H);
    x2 = fminf(fmaxf(x2, 0.f), W);
    y2 = fminf(fmaxf(y2, 0.f), H);
    bool valid = ((x2 - x1) >= 16.f) && ((y2 - y1) >= 16.f);
    float s0 = fl2[lpx * 56 + 36 + a * 2];
    float s1 = fl2[lpx * 56 + 36 + a * 2 + 1];
    float mx = fmaxf(s0, s1);
    float e0 = expf(s0 - mx), e1 = expf(s1 - mx);
    float fg = e1 / (e0 + e1);
    float sc = valid ? fg : -1e9f;
    unsigned bb = __float_as_uint(sc);
    unsigned v = (bb & 0x80000000u) ? ~bb : (bb | 0x80000000u);
    keys[gid] = v;
    *(float4*)(boxes + (size_t)gid * 4) = make_float4(x1, y1, x2, y2);
    unsigned bin = v >> 16;
    unsigned tix = ((bin & 255u) << 8) | (bin >> 8);
    unsigned long long mv = __ballot(!valid);
    if (!valid) {
      int leader = __ffsll(mv) - 1;
      if (lane == leader)
        atomicAdd(&hist[(size_t)n * 65536 + tix], (unsigned)__popcll(mv));
    } else {
      atomicAdd(&hist[(size_t)n * 65536 + tix], 1u);
    }
  }
}

__global__ __launch_bounds__(256) void compact_kernel(
    const unsigned* __restrict__ keys, const unsigned* __restrict__ hist,
    unsigned* __restrict__ cnt, unsigned long long* __restrict__ cand) {
  int t = threadIdx.x;
  int gid = blockIdx.x * 256 + t;
  int lane = t & 63;
  int n = (blockIdx.x << 8) / NANCH;
  int i = gid - n * NANCH;
  const unsigned* h = hist + (size_t)n * 65536;
  __shared__ unsigned csum[256];
  __shared__ unsigned fine[256];
  __shared__ unsigned csel, cumsh, cutsh;
  unsigned s = 0;
  for (int low = 0; low < 256; ++low) s += h[low * 256 + t];
  csum[t] = s;
  __syncthreads();
  if (t == 0) {
    unsigned cum = 0;
    int c = 255;
    for (; c > 0; --c) {
      if (cum + csum[c] >= PREN) break;
      cum += csum[c];
    }
    csel = (unsigned)c;
    cumsh = cum;
  }
  __syncthreads();
  int c = (int)csel;
  fine[t] = h[t * 256 + c];
  __syncthreads();
  if (t == 0) {
    unsigned cum = cumsh;
    unsigned P = (unsigned)(c << 8);
    for (int low = 255; low >= 0; --low) {
      cum += fine[low];
      if (cum >= PREN) { P = (unsigned)((c << 8) | low); break; }
    }
    cutsh = P;
  }
  __syncthreads();
  unsigned P = cutsh;
  unsigned v = keys[gid];
  bool take = (v >> 16) >= P;
  unsigned long long m = __ballot(take);
  if (take) {
    int leader = __ffsll(m) - 1;
    int tot = __popcll(m);
    int pre = __popcll(m & ((lane == 0) ? 0ull : (~0ull >> (64 - lane))));
    unsigned base = 0;
    if (lane == leader) base = atomicAdd(&cnt[n], (unsigned)tot);
    base = __shfl(base, leader);
    cand[(size_t)n * NANCH + base + pre] =
        ((unsigned long long)v << 32) | (unsigned)(~i);
  }
}

__global__ __launch_bounds__(256) void rank2_kernel(
    const unsigned long long* __restrict__ cand, const unsigned* __restrict__ cnt,
    const float* __restrict__ boxes, float* __restrict__ sboxes) {
  int n = blockIdx.y;
  int C = (int)cnt[n];
  if (blockIdx.x * 256 >= C) return;
  int t = threadIdx.x;
  int i = blockIdx.x * 256 + t;
  const unsigned long long* cb = cand + (size_t)n * NANCH;
  unsigned long long Ki = (i < C) ? cb[i] : 0ull;
  __shared__ unsigned long long tile[256];
  int rank = 0;
  for (int t0 = 0; t0 < C; t0 += 256) {
    __syncthreads();
    int j = t0 + t;
    tile[t] = (j < C) ? cb[j] : 0ull;
    __syncthreads();
#pragma unroll 16
    for (int jj = 0; jj < 256; ++jj)
      rank += (tile[jj] > Ki) ? 1 : 0;
  }
  if (i < C && rank < PREN) {
    unsigned orig = ~(unsigned)(Ki & 0xffffffffull);
    float4 bb = *(const float4*)(boxes + ((size_t)n * NANCH + orig) * 4);
    *(float4*)(sboxes + ((size_t)n * PREN + rank) * 4) = bb;
  }
}

__global__ __launch_bounds__(256) void iou_kernel(
    const float* __restrict__ sboxes, unsigned long long* __restrict__ sup) {
#pragma clang fp contract(off)
  int n = blockIdx.y, i = blockIdx.x;
  const float* B = sboxes + (size_t)n * PREN * 4;
  float4 bi = *(const float4*)(B + (size_t)i * 4);
  float area_i = (bi.z - bi.x) * (bi.w - bi.y);
  int lane = threadIdx.x & 63, wv = threadIdx.x >> 6;
  unsigned long long* row = sup + ((size_t)n * PREN + i) * 64;
  for (int w0 = wv; w0 < 64; w0 += 4) {
    int j = w0 * 64 + lane;
    bool p = false;
    if (j < PREN) {
      float4 bj = *(const float4*)(B + (size_t)j * 4);
      float area_j = (bj.z - bj.x) * (bj.w - bj.y);
      float x1 = fmaxf(bi.x, bj.x), y1 = fmaxf(bi.y, bj.y);
      float x2 = fminf(bi.z, bj.z), y2 = fminf(bi.w, bj.w);
      float inter = fmaxf(x2 - x1, 0.f) * fmaxf(y2 - y1, 0.f);
      float iou = inter / (area_i + area_j - inter + 1e-9f);
      p = iou > 0.7f;
    }
    unsigned long long m = __ballot(p);
    if (lane == 0) row[w0] = m;
  }
}

__global__ __launch_bounds__(64) void nms_kernel(
    const unsigned long long* __restrict__ sup, const float* __restrict__ sboxes,
    float* __restrict__ rois, float* __restrict__ ridx) {
  int n = blockIdx.x;
  int lane = threadIdx.x;
  const unsigned long long* S = sup + (size_t)n * PREN * 64;
  unsigned long long buf[64];
#pragma unroll
  for (int bq = 0; bq < 64; ++bq) buf[bq] = S[(size_t)bq * 64 + lane];
  unsigned long long keep = (lane < 46) ? ~0ull
                          : (lane == 46 ? ((1ull << 56) - 1ull) : 0ull);
  for (int w = 0; w < 47; ++w) {
    unsigned long long kw = __shfl(keep, w);
    unsigned long long gtmask = (lane > w) ? ~0ull : 0ull;
#pragma unroll
    for (int bq = 0; bq < 64; ++bq) {
      const int i = w * 64 + bq;
      unsigned long long r = buf[bq];
      if (i + 64 < PREN) buf[bq] = S[(size_t)(i + 64) * 64 + lane];
      unsigned long long rw = __shfl(r, w);
      unsigned long long amask = ((kw >> bq) & 1ull) ? ~0ull : 0ull;
      const unsigned long long fmask = (bq == 63) ? 0ull : ~((2ull << bq) - 1ull);
      kw &= ~(rw & fmask & amask);
      keep &= ~(r & gtmask & amask);
    }
    keep = (lane == w) ? kw : keep;
  }
  int cnt = __popcll(keep);
  int scn = cnt;
  for (int d = 1; d < 64; d <<= 1) {
    int v = __shfl_up(scn, d);
    if (lane >= d) scn += v;
  }
  int excl = scn - cnt;
  int total = __shfl(scn, 63);
  const float* SB = sboxes + (size_t)n * PREN * 4;
  unsigned long long kk = keep;
  int p = excl;
  while (kk) {
    int bpos = __ffsll(kk) - 1;
    kk &= kk - 1ull;
    if (p < POSTN) {
      float4 bb = *(const float4*)(SB + (size_t)(lane * 64 + bpos) * 4);
      *(float4*)(rois + ((size_t)n * POSTN + p) * 4) = bb;
    }
    ++p;
  }
  if (lane == 0) {
    float4 b0 = *(const float4*)SB;
    for (int q = total; q < POSTN; ++q)
      *(float4*)(rois + ((size_t)n * POSTN + q) * 4) = b0;
  }
  for (int q = lane; q < POSTN; q += 64) ridx[n * POSTN + q] = (float)n;
}

extern "C" void kernel_launch(void* const* d_in, const int* in_sizes, int n_in,
                              void* d_out, int out_size, void* d_ws, size_t ws_size,
                              hipStream_t stream) {
  const float* x       = (const float*)d_in[0];
  const float* w_conv  = (const float*)d_in[1];
  const float* b_conv  = (const float*)d_in[2];
  const float* w_score = (const float*)d_in[3];
  const float* b_score = (const float*)d_in[4];
  const float* w_loc   = (const float*)d_in[5];
  const float* b_loc   = (const float*)d_in[6];
  const int*   img_h   = (const int*)d_in[7];
  const int*   img_w   = (const int*)d_in[8];

  float* out        = (float*)d_out;
  float* out_locs   = out;
  float* out_scores = out + 589824;
  float* out_rois   = out + 884736;
  float* out_ridx   = out + 889536;
  float* out_anchor = out + 890736;

  const size_t NEED = 76546112;   // feat2 33.55M | wt 9.44M | xt 33.55M | zpage 64B
  if (ws_size >= NEED) {
    // ---- MFMA path (f16x2 split, B->reg, A dbuf, 1 barrier/icc, rolled) ----
    float* feat2 = (float*)d_ws;                                   // 33,554,432 B
    short* wth   = (short*)((char*)d_ws + 33554432);               //  4,718,592 B
    short* wtl   = wth + 2359296;                                  //  4,718,592 B
    short* xth   = (short*)((char*)d_ws + 42991616);               // 16,777,216 B
    short* xtl   = xth + 8388608;                                  // 16,777,216 B
    char*  zpage = (char*)d_ws + 76546048;                         //         64 B
    // post-conv aliases: boxes region over wt (dead), hist/cand over xt (dead)
    float* boxes = (float*)wth;                                    // 2,359,296 B
    unsigned* keys = (unsigned*)(boxes + 589824);
    float* sboxes  = (float*)(keys + 147456);
    unsigned long long* sup = (unsigned long long*)(sboxes + 48000);
    unsigned* hist = (unsigned*)xth;
    unsigned* cnt  = hist + 262148;
    unsigned long long* cand = (unsigned long long*)(hist + 262160);

    xform_w_kernel<<<512, 256, 0, stream>>>(w_conv, wth, wtl, (unsigned*)zpage);
    xform_x_kernel<<<dim3(64, 4), 256, 0, stream>>>(x, xth, xtl);
    conv3_mfma<<<dim3(32, 4, 4), 256, 0, stream>>>(xth, xtl, wth, wtl, b_conv,
                                                   zpage, feat2);
    zero_hist_kernel<<<1025, 256, 0, stream>>>(hist);
    conv1_decode_kernel<<<dim3(64, 4, 2), 256, 0, stream>>>(
        feat2, w_loc, b_loc, w_score, b_score, img_h, img_w,
        out_locs, out_scores, boxes, keys, hist, out_anchor);
    compact_kernel<<<576, 256, 0, stream>>>(keys, hist, cnt, cand);
    rank2_kernel<<<dim3(144, 4), 256, 0, stream>>>(cand, cnt, boxes, sboxes);
    iou_kernel<<<dim3(PREN, 4), 256, 0, stream>>>(sboxes, sup);
    nms_kernel<<<4, 64, 0, stream>>>(sup, sboxes, out_rois, out_ridx);
  } else {
    // ---- fallback: previous fp32 pipeline (ws too small for MFMA path) ----
    float* feat2 = (float*)d_ws;
    float* A     = feat2 + (size_t)8388608;
    float* w4    = A;
    float* boxes = A;
    unsigned* keys = (unsigned*)(boxes + 589824);
    float* sboxes  = (float*)(keys + 147456);
    unsigned long long* sup = (unsigned long long*)(sboxes + 48000);
    unsigned* hist = (unsigned*)(A + 2359296);
    unsigned* cnt  = hist + 262148;
    unsigned long long* cand = (unsigned long long*)(hist + 262160);

    reshape_w_kernel<<<9216, 256, 0, stream>>>(w_conv, w4, hist);
    conv3_kernel<<<dim3(16, 16, 4), 256, 0, stream>>>(x, w4, b_conv, feat2);
    conv1_decode_kernel<<<dim3(64, 4, 2), 256, 0, stream>>>(
        feat2, w_loc, b_loc, w_score, b_score, img_h, img_w,
        out_locs, out_scores, boxes, keys, hist, out_anchor);
    compact_kernel<<<576, 256, 0, stream>>>(keys, hist, cnt, cand);
    rank2_kernel<<<dim3(144, 4), 256, 0, stream>>>(cand, cnt, boxes, sboxes);
    iou_kernel<<<dim3(PREN, 4), 256, 0, stream>>>(sboxes, sup);
    nms_kernel<<<4, 64, 0, stream>>>(sup, sboxes, out_rois, out_ridx);
  }
}

// Round 11
// 576.952 us; speedup vs baseline: 1.9986x; 1.3007x over previous
//
#include <hip/hip_runtime.h>
#include <cstdint>
#include <cmath>

#define HW 64
#define NPIX 4096          // 64*64
#define CIN 512
#define NANCH 36864        // 4096*9
#define PREN 3000
#define POSTN 300
#define ICL 8
#define NSLOT 13           // ceil(8*6*66 / 256), last slot: 96 threads

typedef _Float16 h8v __attribute__((ext_vector_type(8)));
typedef float f16v __attribute__((ext_vector_type(16)));

#define AS1 __attribute__((address_space(1)))
#define AS3 __attribute__((address_space(3)))

__device__ __forceinline__ void gl16(const void* g, void* l) {
  __builtin_amdgcn_global_load_lds((const AS1 void*)g, (AS3 void*)l, 16, 0, 0);
}

// f16 two-term split: f = h + l with |f-h-l| <= |f|*2^-22 (f pre-scaled so
// both h and l stay in f16 normal range; scaling by 2^k is exact).
__device__ __forceinline__ void f16_split(float f, short& h, short& l) {
  _Float16 hh = (_Float16)f;
  float hf = (float)hh;
  _Float16 ll = (_Float16)(f - hf);
  h = __builtin_bit_cast(short, hh);
  l = __builtin_bit_cast(short, ll);
}

// ==================== MFMA PATH: f16x2-split conv ====================

// ---- w (512oc,512ic,3,3) fp32 -> wth/wtl fragment-major f16 hi/lo, x128 ----
// Layout (shorts): [tap][icc][kh][lh][oc 0..511][8 ic]
__global__ __launch_bounds__(256) void xform_w_kernel(
    const float* __restrict__ w, short* __restrict__ wth,
    short* __restrict__ wtl, unsigned* __restrict__ zp) {
  const int oc = blockIdx.x;
  const int t = threadIdx.x;
  __shared__ float ws_[4608];
  const float* wr = w + (size_t)oc * 4608;
  for (int i = t; i < 4608; i += 256) ws_[i] = wr[i];
  __syncthreads();
  for (int c = t; c < 576; c += 256) {
    int tap = c / 64;
    int g = c - tap * 64;            // ic-group of 8: ic = g*8 .. g*8+7
    int icc = g >> 2;
    int kh = (g >> 1) & 1;
    int lhh = g & 1;
    h8v hv, lv;
    short* hp = (short*)&hv;
    short* lp = (short*)&lv;
#pragma unroll
    for (int j = 0; j < 8; ++j) {
      short hh, ll;
      f16_split(ws_[(g * 8 + j) * 9 + tap] * 128.0f, hh, ll);
      hp[j] = hh; lp[j] = ll;
    }
    long o = (((((long)tap * 16 + icc) * 2 + kh) * 2 + lhh) * 512 + oc) * 8;
    *(h8v*)(wth + o) = hv;
    *(h8v*)(wtl + o) = lv;
  }
  if (oc == 0 && t < 16) zp[t] = 0u;   // zero-page for halo redirect
}

// ---- x NCHW fp32 -> xth/xtl [n][y][x][ic] f16 hi/lo (NHWC), x2048 ----
__global__ __launch_bounds__(256) void xform_x_kernel(
    const float* __restrict__ x, short* __restrict__ xth,
    short* __restrict__ xtl) {
  const int yb = blockIdx.x;   // 0..63
  const int n = blockIdx.y;
  const int t = threadIdx.x;
  __shared__ float xs[64 * 65];
  const float* xr = x + ((size_t)n * 512) * 4096 + yb * 64;
  short* oh = xth + ((size_t)n * 4096 + yb * 64) * 512;
  short* ol = xtl + ((size_t)n * 4096 + yb * 64) * 512;
  for (int icb = 0; icb < 8; ++icb) {
    if (icb) __syncthreads();
#pragma unroll
    for (int q = 0; q < 16; ++q) {
      int idx = q * 256 + t;
      int icl = idx >> 6, xc = idx & 63;
      xs[icl * 65 + xc] = xr[(size_t)(icb * 64 + icl) * 4096 + xc];
    }
    __syncthreads();
#pragma unroll
    for (int q = 0; q < 2; ++q) {
      int c = q * 256 + t;
      int xc = c >> 3, icg = c & 7;
      h8v hv, lv;
      short* hp = (short*)&hv;
      short* lp = (short*)&lv;
#pragma unroll
      for (int j = 0; j < 8; ++j) {
        short hh, ll;
        f16_split(xs[(icg * 8 + j) * 65 + xc] * 2048.0f, hh, ll);
        hp[j] = hh; lp[j] = ll;
      }
      size_t o = (size_t)xc * 512 + icb * 64 + icg * 8;
      *(h8v*)(oh + o) = hv;
      *(h8v*)(ol + o) = lv;
    }
  }
}

// ---- 3x3 conv via implicit GEMM on matrix cores, f16x2 split (3 MFMA) ----
// grid (32 ypair-raw, 4, 4n), 256 thr = 4 waves; block tile 2rows x 64cols x 128oc.
// A-slab: LDS DOUBLE-buffered (69632 B). B: global->VGPR (L2-resident),
// prefetched 1 tap ahead via single Bcur/Bnxt pair. ROLLED 144-step loop
// (unrolled tap loop spills). A restage at tap 0 -> buf^1, 1 barrier/icc.
// Result scaled 2^18; chunked S-drain per icc (bit-identical to R3 order).
__global__ __launch_bounds__(256, 2) void conv3_mfma(
    const short* __restrict__ xth, const short* __restrict__ xtl,
    const short* __restrict__ wth, const short* __restrict__ wtl,
    const float* __restrict__ bconv, const char* __restrict__ zpage,
    float* __restrict__ feat2) {
  const int t = threadIdx.x;
  const int lane = t & 63;
  const int wid = __builtin_amdgcn_readfirstlane(t >> 6);
  const int l31 = lane & 31, lh = lane >> 5;
  const int wm = wid >> 1, wn = wid & 1;

  // XCD-aware swizzle: each XCD (bx%8) owns one 128-oc weight panel (L2-fit).
  const int bx = blockIdx.x, by = blockIdx.y, n = blockIdx.z;
  const int k8 = bx & 7;
  const int ocb = k8 & 3;
  const int yp = (k8 >> 2) * 16 + (bx >> 3) * 4 + by;  // 0..31
  const int y0 = yp * 2;
  const int ocbase = ocb * 128;

  __shared__ short As[2][2][272 * 32];   // [abuf][hilo][...] 69632 B
  char* const asb = (char*)&As[0][0][0];

  // ---- A staging descriptors: 34x 1KB blocks over 4 waves ----
  const char* asrc[9]; int adst[9]; int astep[9];
  {
    const char* xs0 = (const char*)xth;
    const char* xs1 = (const char*)xtl;
#pragma unroll
    for (int k = 0; k < 9; ++k) {
      int bq = wid + 4 * k;
      if (bq < 34) {
        int hl = (bq >= 17) ? 1 : 0;
        int blk = bq - hl * 17;
        int e = blk * 16 + (lane >> 2);
        int slot = lane & 3;
        int r = e / 68;
        int cp = e - r * 68;
        int y = y0 - 1 + r;
        int c = cp - 1;
        bool valid = (cp >= 1) && (cp <= 64) && (y >= 0) && (y < 64);
        int ss = slot ^ ((e >> 1) & 3);                 // source pre-swizzle
        long off = ((((long)n * 64 + y) * 64 + c) * 512 + ss * 8) * 2;
        asrc[k] = valid ? ((hl ? xs1 : xs0) + off) : (const char*)zpage;
        astep[k] = valid ? 64 : 0;                      // 32 ic * 2B per icc
        adst[k] = hl * 17408 + blk * 1024;
      }
    }
  }

  // ---- B fragment global base: lane-constant offset (shorts) ----
  const long lane_b = (long)lh * 4096 + (long)(ocbase + wn * 64 + l31) * 8;

  struct FragB { h8v h[2][2], l[2][2]; };   // [kh][fn]

#define READ_Bg(F, TAP, ICC) do {                                            \
    long sb_ = ((long)(TAP) * 16 + (ICC)) * 16384 + lane_b;                  \
    _Pragma("unroll")                                                        \
    for (int kh_ = 0; kh_ < 2; ++kh_)                                        \
      _Pragma("unroll")                                                      \
      for (int fn_ = 0; fn_ < 2; ++fn_) {                                    \
        long o_ = sb_ + kh_ * 8192 + fn_ * 256;                              \
        (F).h[kh_][fn_] = *(const h8v*)(wth + o_);                           \
        (F).l[kh_][fn_] = *(const h8v*)(wtl + o_);                           \
      }                                                                      \
  } while (0)

#define COMP_AE(AE, TAP) do {                                                 \
    int dy_ = (TAP) / 3, dx_ = (TAP) - dy_ * 3;                               \
    _Pragma("unroll")                                                         \
    for (int fm_ = 0; fm_ < 2; ++fm_) {                                       \
      int e_ = (wm + dy_) * 68 + fm_ * 32 + l31 + dx_;                        \
      (AE)[fm_] = e_ * 64 + ((lh ^ ((e_ >> 1) & 3)) << 4);                    \
    }                                                                         \
  } while (0)

  // per kh: read 4 A granules from LDS (inline), then 12 MFMAs (R3 order).
#define TAP_MFMA(BC, AB) do {                                                 \
    _Pragma("unroll")                                                         \
    for (int kh_ = 0; kh_ < 2; ++kh_) {                                       \
      h8v Ah_[2], Al_[2];                                                     \
      _Pragma("unroll")                                                       \
      for (int fm_ = 0; fm_ < 2; ++fm_) {                                     \
        int a0_ = ae[fm_] ^ (kh_ << 5);                                       \
        Ah_[fm_] = *(const h8v*)((AB) + a0_);                                 \
        Al_[fm_] = *(const h8v*)((AB) + 17408 + a0_);                         \
      }                                                                       \
      _Pragma("unroll")                                                       \
      for (int fm_ = 0; fm_ < 2; ++fm_)                                       \
        _Pragma("unroll")                                                     \
        for (int fn_ = 0; fn_ < 2; ++fn_)                                     \
          acc[fm_][fn_] = __builtin_amdgcn_mfma_f32_32x32x16_f16(             \
              Ah_[fm_], (BC).h[kh_][fn_], acc[fm_][fn_], 0, 0, 0);            \
      _Pragma("unroll")                                                       \
      for (int fm_ = 0; fm_ < 2; ++fm_)                                       \
        _Pragma("unroll")                                                     \
        for (int fn_ = 0; fn_ < 2; ++fn_)                                     \
          acc[fm_][fn_] = __builtin_amdgcn_mfma_f32_32x32x16_f16(             \
              Al_[fm_], (BC).h[kh_][fn_], acc[fm_][fn_], 0, 0, 0);            \
      _Pragma("unroll")                                                       \
      for (int fm_ = 0; fm_ < 2; ++fm_)                                       \
        _Pragma("unroll")                                                     \
        for (int fn_ = 0; fn_ < 2; ++fn_)                                     \
          acc[fm_][fn_] = __builtin_amdgcn_mfma_f32_32x32x16_f16(             \
              Ah_[fm_], (BC).l[kh_][fn_], acc[fm_][fn_], 0, 0, 0);            \
    }                                                                         \
  } while (0)

  // Rolled step body (R7 shape). A restage at tap 0 -> buf^1; one barrier.
#define STEP_BODY(BC, BN) do {                                                \
    int tapN_ = tap + 1, iccN_ = icc;                                         \
    if (tapN_ == 9) { tapN_ = 0; iccN_ = (icc < 15) ? icc + 1 : 15; }         \
    READ_Bg(BN, tapN_, iccN_);            /* per-wave B prefetch (1 ahead) */ \
    if (tap == 0 && icc < 15) {           /* stage NEXT icc A -> other buf */ \
      char* ab_ = asb + ((acur ^ 1) * 34816);                                 \
      _Pragma("unroll")                                                       \
      for (int k_ = 0; k_ < 9; ++k_) {                                        \
        int bq_ = wid + 4 * k_;                                               \
        if (bq_ < 34) { asrc[k_] += astep[k_];                                \
                        gl16(asrc[k_], ab_ + adst[k_]); }                     \
      }                                                                       \
    }                                                                         \
    COMP_AE(ae, tap);                                                         \
    { char* abc_ = asb + (acur * 34816);                                      \
      TAP_MFMA(BC, abc_); }                                                   \
    ++tap;                                                                    \
    if (tap == 9) {                       /* icc boundary */                  \
      tap = 0; ++icc;                                                         \
      _Pragma("unroll")                                                       \
      for (int fm_ = 0; fm_ < 2; ++fm_)                                       \
        _Pragma("unroll")                                                     \
        for (int fn_ = 0; fn_ < 2; ++fn_)                                     \
          _Pragma("unroll")                                                   \
          for (int r_ = 0; r_ < 16; ++r_) {                                   \
            S[fm_][fn_][r_] += acc[fm_][fn_][r_];                             \
            acc[fm_][fn_][r_] = 0.f;                                          \
          }                                                                   \
      __syncthreads();                    /* reads done; gl16s 9 taps old */  \
      acur ^= 1;                                                              \
    }                                                                         \
  } while (0)

  f16v acc[2][2];   // per-icc chunk accumulator (MFMA C)
  f16v S[2][2];     // running sum across chunks
#pragma unroll
  for (int i = 0; i < 2; ++i)
#pragma unroll
    for (int j = 0; j < 2; ++j)
#pragma unroll
      for (int r = 0; r < 16; ++r) { acc[i][j][r] = 0.f; S[i][j][r] = 0.f; }

  // prologue: A(icc=0) -> buf0; B(0,0) -> regs
#pragma unroll
  for (int k = 0; k < 9; ++k) {
    int bq = wid + 4 * k;
    if (bq < 34) gl16(asrc[k], asb + adst[k]);
  }
  FragB B0, B1;
  READ_Bg(B0, 0, 0);
  __syncthreads();
  int ae[2];
  int tap = 0, icc = 0, acur = 0;

  for (int s2 = 0; s2 < 72; ++s2) {       // 144 steps, rolled ping-pong
    STEP_BODY(B0, B1);
    STEP_BODY(B1, B0);
  }

#undef READ_Bg
#undef COMP_AE
#undef TAP_MFMA
#undef STEP_BODY

  // ---- epilogue: unscale + bias + ReLU -> feat2 NHWC ----
  const float OS = 1.0f / 262144.0f;       // 2^-18 (x*2^11 * w*2^7)
  const float* bb = bconv + ocbase + wn * 64;
#pragma unroll
  for (int fn = 0; fn < 2; ++fn) {
    const float bias = bb[fn * 32 + l31];
#pragma unroll
    for (int fm = 0; fm < 2; ++fm) {
      float* op = feat2 + (((long)n * 4096 + (y0 + wm) * 64 + fm * 32) * 512)
                + ocbase + wn * 64 + fn * 32 + l31;
#pragma unroll
      for (int r = 0; r < 16; ++r) {
        int m = (r & 3) + 8 * (r >> 2) + 4 * lh;
        op[(long)m * 512] = fmaxf(S[fm][fn][r] * OS + bias, 0.f);
      }
    }
  }
}

__global__ __launch_bounds__(256) void zero_hist_kernel(unsigned* __restrict__ h) {
  int i = blockIdx.x * 256 + threadIdx.x;
  if (i < 262160) h[i] = 0u;
}

// ============== OLD PATH (fallback if ws_size is too small) ==============
__global__ __launch_bounds__(256) void reshape_w_kernel(
    const float* __restrict__ w, float* __restrict__ w4,
    unsigned* __restrict__ histz) {
  int gid = blockIdx.x * 256 + threadIdx.x;
  if (gid < 262160) histz[gid] = 0;
  if (gid >= 512 * 512 * 9) return;
  int o4  = gid & 3;
  int r   = gid >> 2;
  int tap = r % 9;
  int r2  = r / 9;
  int h   = r2 & 1;
  int r3  = r2 >> 1;
  int ic  = r3 & 511;
  int g   = r3 >> 9;
  int oc  = (g >> 2) * 32 + (g & 3) * 8 + h * 4 + o4;
  w4[gid] = w[((size_t)oc * 512 + ic) * 9 + tap];
}

#define WLOAD(DST, UPTR) do {                                                \
    _Pragma("unroll")                                                        \
    for (int q = 0; q < 36; ++q) (DST)[q] = (UPTR)[q];                       \
  } while (0)

#define CONV_HALF(W, OB) do {                                                \
    _Pragma("unroll")                                                        \
    for (int r = 0; r < 3; ++r)                                              \
    _Pragma("unroll")                                                        \
    for (int kx = 0; kx < 3; ++kx) {                                         \
      _Pragma("unroll")                                                      \
      for (int o = 0; o < 4; ++o) {                                          \
        const float wv = (W)[(r * 3 + kx) * 4 + o];                          \
        _Pragma("unroll")                                                    \
        for (int j = 0; j < 4; ++j)                                          \
          acc[(OB) + o][j] = fmaf(wv, xr[r][j + kx], acc[(OB) + o][j]);      \
      }                                                                      \
    }                                                                        \
  } while (0)

__global__ __launch_bounds__(256, 4) void conv3_kernel(
    const float* __restrict__ x, const float* __restrict__ w4,
    const float* __restrict__ b, float* __restrict__ feat2) {
  const int oct = blockIdx.x;
  const int yt  = blockIdx.y;
  const int n   = blockIdx.z;
  const int t   = threadIdx.x;
  const int wid  = __builtin_amdgcn_readfirstlane(t >> 6);
  const int lane = t & 63;
  const int lrow = lane >> 4;
  const int lcol = (lane & 15) << 2;
  const int y0 = yt << 2;

  __shared__ float xs[2][ICL * 6 * 68];

  float acc[8][4];
#pragma unroll
  for (int o = 0; o < 8; ++o)
#pragma unroll
    for (int j = 0; j < 4; ++j) acc[o][j] = 0.f;

  const float* xb = x + (size_t)n * CIN * NPIX;
  const float* __restrict__ wq = w4 + (size_t)(oct * 4 + wid) * (512 * 72);

  int  goff[NSLOT];
  int  laddr[NSLOT];
  bool val[NSLOT];
#pragma unroll
  for (int k = 0; k < NSLOT; ++k) {
    int s   = t + (k << 8);
    int icl = s / 396;
    int rem = s - icl * 396;
    int row = rem / 66;
    int c   = rem - row * 66;
    int yy = y0 - 1 + row;
    int xx = c - 1;
    bool act = (k < NSLOT - 1) || (t < 96);
    val[k]  = act && ((unsigned)yy < 64u) && ((unsigned)xx < 64u);
    goff[k] = icl * NPIX + yy * 64 + xx;
    laddr[k] = icl * 408 + row * 68 + c;
  }

  {
    float v[NSLOT];
#pragma unroll
    for (int k = 0; k < NSLOT; ++k) v[k] = val[k] ? xb[goff[k]] : 0.f;
#pragma unroll
    for (int k = 0; k < NSLOT; ++k)
      if (k < NSLOT - 1 || t < 96) xs[0][laddr[k]] = v[k];
  }

  float wbA[36], wbB[36];
  WLOAD(wbA, wq);

  for (int cch = 0; cch < 64; ++cch) {
    const int cur = cch & 1;
    float rn[NSLOT];
    if (cch < 63) {
      const float* xn = xb + (size_t)(cch + 1) * (ICL * NPIX);
#pragma unroll
      for (int k = 0; k < NSLOT; ++k) rn[k] = val[k] ? xn[goff[k]] : 0.f;
    }
    __syncthreads();
#pragma unroll 1
    for (int icl = 0; icl < ICL; ++icl) {
      const int u0 = (cch << 4) + (icl << 1);
      const float* xp = &xs[cur][icl * 408 + lrow * 68 + lcol];
      float4 a0 = *(const float4*)(xp);
      float2 b0 = *(const float2*)(xp + 4);
      float4 a1 = *(const float4*)(xp + 68);
      float2 b1 = *(const float2*)(xp + 72);
      float4 a2 = *(const float4*)(xp + 136);
      float2 b2 = *(const float2*)(xp + 140);
      float xr[3][6] = {{a0.x, a0.y, a0.z, a0.w, b0.x, b0.y},
                        {a1.x, a1.y, a1.z, a1.w, b1.x, b1.y},
                        {a2.x, a2.y, a2.z, a2.w, b2.x, b2.y}};
      WLOAD(wbB, wq + (size_t)(u0 + 1) * 36);
      CONV_HALF(wbA, 0);
      {
        const int un = (u0 + 2 < 1024) ? (u0 + 2) : 1023;
        WLOAD(wbA, wq + (size_t)un * 36);
      }
      CONV_HALF(wbB, 4);
    }
    if (cch < 63) {
#pragma unroll
      for (int k = 0; k < NSLOT; ++k)
        if (k < NSLOT - 1 || t < 96) xs[cur ^ 1][laddr[k]] = rn[k];
    }
  }

  const float* __restrict__ bs = b + oct * 32 + wid * 8;
  float bias[8];
#pragma unroll
  for (int o = 0; o < 8; ++o) bias[o] = bs[o];
  float* ob = feat2 + ((size_t)n * NPIX + (y0 + lrow) * 64 + lcol) * 512 + oct * 32 + wid * 8;
#pragma unroll
  for (int j = 0; j < 4; ++j) {
    float4 v0, v1;
    v0.x = fmaxf(acc[0][j] + bias[0], 0.f);
    v0.y = fmaxf(acc[1][j] + bias[1], 0.f);
    v0.z = fmaxf(acc[2][j] + bias[2], 0.f);
    v0.w = fmaxf(acc[3][j] + bias[3], 0.f);
    v1.x = fmaxf(acc[4][j] + bias[4], 0.f);
    v1.y = fmaxf(acc[5][j] + bias[5], 0.f);
    v1.z = fmaxf(acc[6][j] + bias[6], 0.f);
    v1.w = fmaxf(acc[7][j] + bias[7], 0.f);
    *(float4*)(ob + (size_t)j * 512)     = v0;
    *(float4*)(ob + (size_t)j * 512 + 4) = v1;
  }
}

// ================= shared tail kernels =================
__global__ __launch_bounds__(256) void conv1_decode_kernel(
    const float* __restrict__ feat2,
    const float* __restrict__ w_loc, const float* __restrict__ b_loc,
    const float* __restrict__ w_score, const float* __restrict__ b_score,
    const int* __restrict__ ih, const int* __restrict__ iw,
    float* __restrict__ out_locs, float* __restrict__ out_scores,
    float* __restrict__ boxes, unsigned* __restrict__ keys,
    unsigned* __restrict__ hist, float* __restrict__ out_anchor) {
#pragma clang fp contract(off)
  const int y  = blockIdx.x, n = blockIdx.y, hf = blockIdx.z;
  const int t = threadIdx.x;
  const int lane = t & 63;
  const int pg = t >> 4;
  const int cg = t & 15;
  __shared__ float fl2[128 * 34];
  __shared__ float wl2[128 * 64];
  float acc[2][4];
#pragma unroll
  for (int i = 0; i < 2; ++i)
#pragma unroll
    for (int j = 0; j < 4; ++j) acc[i][j] = 0.f;

  const float* fb = feat2 + ((size_t)n * NPIX + y * 64 + hf * 32) * 512;
  for (int ch = 0; ch < 512; ch += 128) {
    for (int idx = t; idx < 32 * 128; idx += 256) {
      int p = idx >> 7, ic = idx & 127;
      fl2[ic * 34 + p] = fb[(size_t)p * 512 + ch + ic];
    }
    for (int idx = t; idx < 64 * 128; idx += 256) {
      int c = idx & 63, ic = idx >> 6;
      float v = 0.f;
      if (c < 36) v = w_loc[c * 512 + ch + ic];
      else if (c < 54) v = w_score[(c - 36) * 512 + ch + ic];
      wl2[ic * 64 + c] = v;
    }
    __syncthreads();
#pragma unroll 4
    for (int ic = 0; ic < 128; ++ic) {
      float2 f = *(const float2*)&fl2[ic * 34 + pg * 2];
      float4 w = *(const float4*)&wl2[ic * 64 + cg * 4];
      float fv[2] = {f.x, f.y};
      float wv[4] = {w.x, w.y, w.z, w.w};
#pragma unroll
      for (int i = 0; i < 2; ++i)
#pragma unroll
        for (int j = 0; j < 4; ++j)
          acc[i][j] = fmaf(wv[j], fv[i], acc[i][j]);
    }
    __syncthreads();
  }
#pragma unroll
  for (int j = 0; j < 4; ++j) {
    int c = cg * 4 + j;
    float bias = (c < 36) ? b_loc[c] : (c < 54 ? b_score[c - 36] : 0.f);
#pragma unroll
    for (int i = 0; i < 2; ++i) {
      int pxl = pg * 2 + i;
      float v = acc[i][j] + bias;
      size_t pix0 = (size_t)y * 64 + hf * 32 + pxl;
      if (c < 36) {
        out_locs[((size_t)n * NPIX + pix0) * 36 + c] = v;
        fl2[pxl * 56 + c] = v;
      } else if (c < 54) {
        out_scores[((size_t)n * NPIX + pix0) * 18 + (c - 36)] = v;
        fl2[pxl * 56 + c] = v;
      }
    }
  }
  __syncthreads();
  for (int task = t; task < 288; task += 256) {
    int lpx = task / 9;
    int a   = task - lpx * 9;
    int xq = hf * 32 + lpx, yq = y;
    int i = (yq * 64 + xq) * 9 + a;
    int gid = n * NANCH + i;
    int ri = a / 3, si = a - ri * 3;
    double ratio = (ri == 0) ? 0.5 : (ri == 1 ? 1.0 : 2.0);
    double scl   = (si == 0) ? 8.0 : (si == 1 ? 16.0 : 32.0);
    double hh = 16.0 * scl * sqrt(ratio);
    double ww = 16.0 * scl * sqrt(1.0 / ratio);
    float sx = (float)(xq * 16), sy = (float)(yq * 16);
    float ax1 = (float)(8.0 - ww * 0.5) + sx;
    float ay1 = (float)(8.0 - hh * 0.5) + sy;
    float ax2 = (float)(8.0 + ww * 0.5) + sx;
    float ay2 = (float)(8.0 + hh * 0.5) + sy;
    if (n == 0) {
      *(float4*)(out_anchor + (size_t)i * 4) = make_float4(ax1, ay1, ax2, ay2);
    }
    float l0 = fl2[lpx * 56 + a * 4 + 0];
    float l1 = fl2[lpx * 56 + a * 4 + 1];
    float l2 = fl2[lpx * 56 + a * 4 + 2];
    float l3 = fl2[lpx * 56 + a * 4 + 3];
    float aw = ax2 - ax1, ah = ay2 - ay1;
    float cx = ax1 + 0.5f * aw, cy = ay1 + 0.5f * ah;
    float ctrx = l0 * aw + cx, ctry = l1 * ah + cy;
    float nw = expf(l2) * aw, nh = expf(l3) * ah;
    float x1 = ctrx - 0.5f * nw, y1 = ctry - 0.5f * nh;
    float x2 = ctrx + 0.5f * nw, y2 = ctry + 0.5f * nh;
    float W = (float)iw[0], H = (float)ih[0];
    x1 = fminf(fmaxf(x1, 0.f), W);
    y1 = fminf(fmaxf(y1, 0.f), H);
    x2 = fminf(fmaxf(x2, 0.f), W);
    y2 = fminf(fmaxf(y2, 0.f), H);
    bool valid = ((x2 - x1) >= 16.f) && ((y2 - y1) >= 16.f);
    float s0 = fl2[lpx * 56 + 36 + a * 2];
    float s1 = fl2[lpx * 56 + 36 + a * 2 + 1];
    float mx = fmaxf(s0, s1);
    float e0 = expf(s0 - mx), e1 = expf(s1 - mx);
    float fg = e1 / (e0 + e1);
    float sc = valid ? fg : -1e9f;
    unsigned bb = __float_as_uint(sc);
    unsigned v = (bb & 0x80000000u) ? ~bb : (bb | 0x80000000u);
    keys[gid] = v;
    *(float4*)(boxes + (size_t)gid * 4) = make_float4(x1, y1, x2, y2);
    unsigned bin = v >> 16;
    unsigned tix = ((bin & 255u) << 8) | (bin >> 8);
    unsigned long long mv = __ballot(!valid);
    if (!valid) {
      int leader = __ffsll(mv) - 1;
      if (lane == leader)
        atomicAdd(&hist[(size_t)n * 65536 + tix], (unsigned)__popcll(mv));
    } else {
      atomicAdd(&hist[(size_t)n * 65536 + tix], 1u);
    }
  }
}

__global__ __launch_bounds__(256) void compact_kernel(
    const unsigned* __restrict__ keys, const unsigned* __restrict__ hist,
    unsigned* __restrict__ cnt, unsigned long long* __restrict__ cand) {
  int t = threadIdx.x;
  int gid = blockIdx.x * 256 + t;
  int lane = t & 63;
  int n = (blockIdx.x << 8) / NANCH;
  int i = gid - n * NANCH;
  const unsigned* h = hist + (size_t)n * 65536;
  __shared__ unsigned csum[256];
  __shared__ unsigned fine[256];
  __shared__ unsigned csel, cumsh, cutsh;
  unsigned s = 0;
  for (int low = 0; low < 256; ++low) s += h[low * 256 + t];
  csum[t] = s;
  __syncthreads();
  if (t == 0) {
    unsigned cum = 0;
    int c = 255;
    for (; c > 0; --c) {
      if (cum + csum[c] >= PREN) break;
      cum += csum[c];
    }
    csel = (unsigned)c;
    cumsh = cum;
  }
  __syncthreads();
  int c = (int)csel;
  fine[t] = h[t * 256 + c];
  __syncthreads();
  if (t == 0) {
    unsigned cum = cumsh;
    unsigned P = (unsigned)(c << 8);
    for (int low = 255; low >= 0; --low) {
      cum += fine[low];
      if (cum >= PREN) { P = (unsigned)((c << 8) | low); break; }
    }
    cutsh = P;
  }
  __syncthreads();
  unsigned P = cutsh;
  unsigned v = keys[gid];
  bool take = (v >> 16) >= P;
  unsigned long long m = __ballot(take);
  if (take) {
    int leader = __ffsll(m) - 1;
    int tot = __popcll(m);
    int pre = __popcll(m & ((lane == 0) ? 0ull : (~0ull >> (64 - lane))));
    unsigned base = 0;
    if (lane == leader) base = atomicAdd(&cnt[n], (unsigned)tot);
    base = __shfl(base, leader);
    cand[(size_t)n * NANCH + base + pre] =
        ((unsigned long long)v << 32) | (unsigned)(~i);
  }
}

__global__ __launch_bounds__(256) void rank2_kernel(
    const unsigned long long* __restrict__ cand, const unsigned* __restrict__ cnt,
    const float* __restrict__ boxes, float* __restrict__ sboxes) {
  int n = blockIdx.y;
  int C = (int)cnt[n];
  if (blockIdx.x * 256 >= C) return;
  int t = threadIdx.x;
  int i = blockIdx.x * 256 + t;
  const unsigned long long* cb = cand + (size_t)n * NANCH;
  unsigned long long Ki = (i < C) ? cb[i] : 0ull;
  __shared__ unsigned long long tile[256];
  int rank = 0;
  for (int t0 = 0; t0 < C; t0 += 256) {
    __syncthreads();
    int j = t0 + t;
    tile[t] = (j < C) ? cb[j] : 0ull;
    __syncthreads();
#pragma unroll 16
    for (int jj = 0; jj < 256; ++jj)
      rank += (tile[jj] > Ki) ? 1 : 0;
  }
  if (i < C && rank < PREN) {
    unsigned orig = ~(unsigned)(Ki & 0xffffffffull);
    float4 bb = *(const float4*)(boxes + ((size_t)n * NANCH + orig) * 4);
    *(float4*)(sboxes + ((size_t)n * PREN + rank) * 4) = bb;
  }
}

__global__ __launch_bounds__(256) void iou_kernel(
    const float* __restrict__ sboxes, unsigned long long* __restrict__ sup) {
#pragma clang fp contract(off)
  int n = blockIdx.y, i = blockIdx.x;
  const float* B = sboxes + (size_t)n * PREN * 4;
  float4 bi = *(const float4*)(B + (size_t)i * 4);
  float area_i = (bi.z - bi.x) * (bi.w - bi.y);
  int lane = threadIdx.x & 63, wv = threadIdx.x >> 6;
  unsigned long long* row = sup + ((size_t)n * PREN + i) * 64;
  for (int w0 = wv; w0 < 64; w0 += 4) {
    int j = w0 * 64 + lane;
    bool p = false;
    if (j < PREN) {
      float4 bj = *(const float4*)(B + (size_t)j * 4);
      float area_j = (bj.z - bj.x) * (bj.w - bj.y);
      float x1 = fmaxf(bi.x, bj.x), y1 = fmaxf(bi.y, bj.y);
      float x2 = fminf(bi.z, bj.z), y2 = fminf(bi.w, bj.w);
      float inter = fmaxf(x2 - x1, 0.f) * fmaxf(y2 - y1, 0.f);
      float iou = inter / (area_i + area_j - inter + 1e-9f);
      p = iou > 0.7f;
    }
    unsigned long long m = __ballot(p);
    if (lane == 0) row[w0] = m;
  }
}

// -------- word-wise greedy sweep, R11: serial/parallel split --------------
// Exact-equivalent restructure: within a word, a candidate's keep bit is
// frozen by the time it is processed (fmask clears only FUTURE bits), so the
// cross-word suppression can use the FINAL kw. Per word: (0) 64 independent
// shfls extract the diagonal block; (1) 64-step pure-ALU serial chain; (2)
// parallel cross-word suppression + refill. Early exit once >=300 kept
// (kw is wave-uniform so the running total is scalar).
__global__ __launch_bounds__(64) void nms_kernel(
    const unsigned long long* __restrict__ sup, const float* __restrict__ sboxes,
    float* __restrict__ rois, float* __restrict__ ridx) {
  int n = blockIdx.x;
  int lane = threadIdx.x;
  const unsigned long long* S = sup + (size_t)n * PREN * 64;
  unsigned long long buf[64];
#pragma unroll
  for (int bq = 0; bq < 64; ++bq) buf[bq] = S[(size_t)bq * 64 + lane];
  unsigned long long keep = (lane < 46) ? ~0ull
                          : (lane == 46 ? ((1ull << 56) - 1ull) : 0ull);  // 3000 bits
  int tot = 0;
  for (int w = 0; w < 47; ++w) {
    // phase 0: diagonal-block words (independent shfls, latency pipelines)
    unsigned long long rw[64];
#pragma unroll
    for (int bq = 0; bq < 64; ++bq) rw[bq] = __shfl(buf[bq], w);
    // phase 1: serial in-word chain (pure ALU, ~4 ops/step)
    unsigned long long kw = __shfl(keep, w);
#pragma unroll
    for (int bq = 0; bq < 64; ++bq) {
      unsigned long long amask = ((kw >> bq) & 1ull) ? ~0ull : 0ull;
      const unsigned long long fmask = (bq == 63) ? 0ull : ~((2ull << bq) - 1ull);
      kw &= ~(rw[bq] & fmask & amask);
    }
    // phase 2: cross-word suppression with FINAL kw (parallel) + refill
    unsigned long long gmask = (lane > w) ? ~0ull : 0ull;
#pragma unroll
    for (int bq = 0; bq < 64; ++bq) {
      unsigned long long amask = ((kw >> bq) & 1ull) ? ~0ull : 0ull;
      keep &= ~(buf[bq] & gmask & amask);
      const int i = w * 64 + bq;
      if (i + 64 < PREN) buf[bq] = S[(size_t)(i + 64) * 64 + lane];
    }
    keep = (lane == w) ? kw : keep;
    tot += __popcll(kw);                  // kw is wave-uniform
    if (tot >= POSTN) {                   // first 300 kept fully determined
      if (lane > w) keep = 0ull;          // unprocessed words irrelevant
      break;
    }
  }
  int cnt = __popcll(keep);
  int scn = cnt;
  for (int d = 1; d < 64; d <<= 1) {
    int v = __shfl_up(scn, d);
    if (lane >= d) scn += v;
  }
  int excl = scn - cnt;
  int total = __shfl(scn, 63);
  const float* SB = sboxes + (size_t)n * PREN * 4;
  unsigned long long kk = keep;
  int p = excl;
  while (kk) {
    int bpos = __ffsll(kk) - 1;
    kk &= kk - 1ull;
    if (p < POSTN) {
      float4 bb = *(const float4*)(SB + (size_t)(lane * 64 + bpos) * 4);
      *(float4*)(rois + ((size_t)n * POSTN + p) * 4) = bb;
    }
    ++p;
  }
  if (lane == 0) {
    float4 b0 = *(const float4*)SB;
    for (int q = total; q < POSTN; ++q)
      *(float4*)(rois + ((size_t)n * POSTN + q) * 4) = b0;
  }
  for (int q = lane; q < POSTN; q += 64) ridx[n * POSTN + q] = (float)n;
}

extern "C" void kernel_launch(void* const* d_in, const int* in_sizes, int n_in,
                              void* d_out, int out_size, void* d_ws, size_t ws_size,
                              hipStream_t stream) {
  const float* x       = (const float*)d_in[0];
  const float* w_conv  = (const float*)d_in[1];
  const float* b_conv  = (const float*)d_in[2];
  const float* w_score = (const float*)d_in[3];
  const float* b_score = (const float*)d_in[4];
  const float* w_loc   = (const float*)d_in[5];
  const float* b_loc   = (const float*)d_in[6];
  const int*   img_h   = (const int*)d_in[7];
  const int*   img_w   = (const int*)d_in[8];

  float* out        = (float*)d_out;
  float* out_locs   = out;
  float* out_scores = out + 589824;
  float* out_rois   = out + 884736;
  float* out_ridx   = out + 889536;
  float* out_anchor = out + 890736;

  const size_t NEED = 76546112;   // feat2 33.55M | wt 9.44M | xt 33.55M | zpage 64B
  if (ws_size >= NEED) {
    // ---- MFMA path (f16x2 split, B->reg, A dbuf, 1 barrier/icc, rolled) ----
    float* feat2 = (float*)d_ws;                                   // 33,554,432 B
    short* wth   = (short*)((char*)d_ws + 33554432);               //  4,718,592 B
    short* wtl   = wth + 2359296;                                  //  4,718,592 B
    short* xth   = (short*)((char*)d_ws + 42991616);               // 16,777,216 B
    short* xtl   = xth + 8388608;                                  // 16,777,216 B
    char*  zpage = (char*)d_ws + 76546048;                         //         64 B
    // post-conv aliases: boxes region over wt (dead), hist/cand over xt (dead)
    float* boxes = (float*)wth;                                    // 2,359,296 B
    unsigned* keys = (unsigned*)(boxes + 589824);
    float* sboxes  = (float*)(keys + 147456);
    unsigned long long* sup = (unsigned long long*)(sboxes + 48000);
    unsigned* hist = (unsigned*)xth;
    unsigned* cnt  = hist + 262148;
    unsigned long long* cand = (unsigned long long*)(hist + 262160);

    xform_w_kernel<<<512, 256, 0, stream>>>(w_conv, wth, wtl, (unsigned*)zpage);
    xform_x_kernel<<<dim3(64, 4), 256, 0, stream>>>(x, xth, xtl);
    conv3_mfma<<<dim3(32, 4, 4), 256, 0, stream>>>(xth, xtl, wth, wtl, b_conv,
                                                   zpage, feat2);
    zero_hist_kernel<<<1025, 256, 0, stream>>>(hist);
    conv1_decode_kernel<<<dim3(64, 4, 2), 256, 0, stream>>>(
        feat2, w_loc, b_loc, w_score, b_score, img_h, img_w,
        out_locs, out_scores, boxes, keys, hist, out_anchor);
    compact_kernel<<<576, 256, 0, stream>>>(keys, hist, cnt, cand);
    rank2_kernel<<<dim3(144, 4), 256, 0, stream>>>(cand, cnt, boxes, sboxes);
    iou_kernel<<<dim3(PREN, 4), 256, 0, stream>>>(sboxes, sup);
    nms_kernel<<<4, 64, 0, stream>>>(sup, sboxes, out_rois, out_ridx);
  } else {
    // ---- fallback: previous fp32 pipeline (ws too small for MFMA path) ----
    float* feat2 = (float*)d_ws;
    float* A     = feat2 + (size_t)8388608;
    float* w4    = A;
    float* boxes = A;
    unsigned* keys = (unsigned*)(boxes + 589824);
    float* sboxes  = (float*)(keys + 147456);
    unsigned long long* sup = (unsigned long long*)(sboxes + 48000);
    unsigned* hist = (unsigned*)(A + 2359296);
    unsigned* cnt  = hist + 262148;
    unsigned long long* cand = (unsigned long long*)(hist + 262160);

    reshape_w_kernel<<<9216, 256, 0, stream>>>(w_conv, w4, hist);
    conv3_kernel<<<dim3(16, 16, 4), 256, 0, stream>>>(x, w4, b_conv, feat2);
    conv1_decode_kernel<<<dim3(64, 4, 2), 256, 0, stream>>>(
        feat2, w_loc, b_loc, w_score, b_score, img_h, img_w,
        out_locs, out_scores, boxes, keys, hist, out_anchor);
    compact_kernel<<<576, 256, 0, stream>>>(keys, hist, cnt, cand);
    rank2_kernel<<<dim3(144, 4), 256, 0, stream>>>(cand, cnt, boxes, sboxes);
    iou_kernel<<<dim3(PREN, 4), 256, 0, stream>>>(sboxes, sup);
    nms_kernel<<<4, 64, 0, stream>>>(sup, sboxes, out_rois, out_ridx);
  }
}